// Round 19
// baseline (283.221 us; speedup 1.0000x reference)
//
#include <hip/hip_runtime.h>
#include <hip/hip_bf16.h>

typedef unsigned short ushort_t;
typedef __attribute__((ext_vector_type(8))) _Float16 half8;
typedef __attribute__((ext_vector_type(4))) _Float16 half4;
typedef __attribute__((ext_vector_type(4))) float f32x4;

// Problem constants
#define NB    16
#define NC    256
#define NHW   4096
#define NPIX  65536
#define NE    1024
#define BETA  0.25f
#define DECAY 0.99f
#define EPS_  1e-5f
#define GAP_FLAG 1.25e-4f

// d_out layout (floats)
#define OFF_LOSS 16777216
#define OFF_IDXF 16777217
#define OFF_NCS  16842753
#define OFF_NEA  16843777
#define OFF_NW   17105921

// ws layout (float offsets)
#define WS_WSUM  0
#define WS_CSSM  1024
#define WS_LPART 2048                     // 2048 floats (per-code,2 parts)
#define WS_CNT   4096
#define WS_FLAGS 4128
#define WS_LIST  6176                     // 65536 u16 = 32768 floats
#define WS_WF16  40960                    // 1024*256 fp16
#define WS_ZF16  (WS_WF16 + 131072)       // 65536*256 fp16
#define WS_IDXI  (WS_ZF16 + 8388608)      // 65536 int
#define WS_CCNT  (WS_IDXI + 65536)        // 1024 int
#define WS_OFFS  (WS_CCNT + 1024)         // 1024 int
#define WS_CUR   (WS_OFFS + 1024)         // 1024 int
#define WS_SORT  (WS_CUR + 1024)          // 65536 int
#define WS_END   (WS_SORT + 65536)

__device__ __forceinline__ float sq_nofma(float x) {
    float s = x * x;
    asm volatile("" : "+v"(s));
    return s;
}

__device__ __forceinline__ float np_pair128_sq(const float* __restrict__ a) {
    float r[8];
    #pragma unroll
    for (int m = 0; m < 8; ++m) r[m] = sq_nofma(a[m]);
    for (int i = 8; i < 128; i += 8) {
        #pragma unroll
        for (int m = 0; m < 8; ++m) r[m] += sq_nofma(a[i + m]);
    }
    return ((r[0] + r[1]) + (r[2] + r[3])) + ((r[4] + r[5]) + (r[6] + r[7]));
}

__device__ __forceinline__ void gload16(const void* g, void* ldsp) {
    __builtin_amdgcn_global_load_lds((const __attribute__((address_space(1))) unsigned int*)g,
                                     (__attribute__((address_space(3))) unsigned int*)ldsp,
                                     16, 0, 0);
}

// ---- K0b: wsum + init of ncs/cnt/ccount/lpart ------------------------------
__global__ __launch_bounds__(64) void wsum_kernel(const float* __restrict__ w,
                                                  float* __restrict__ wsum,
                                                  float* __restrict__ ncs,
                                                  int* __restrict__ cnt,
                                                  int* __restrict__ ccount,
                                                  float* __restrict__ lpart) {
    int j = blockIdx.x * 64 + threadIdx.x;
    const float* wr = w + (size_t)j * NC;
    wsum[j] = np_pair128_sq(wr) + np_pair128_sq(wr + 128);
    ncs[j] = 0.0f;
    ccount[j] = 0;
    lpart[j] = 0.0f;
    lpart[j + 1024] = 0.0f;
    if (j == 0) cnt[0] = 0;
}

// ---- P1: pack w -> fp16, scaled by 1024 ------------------------------------
__global__ __launch_bounds__(256) void wpack_kernel(const float* __restrict__ w,
                                                    _Float16* __restrict__ wf) {
    int i = blockIdx.x * 256 + threadIdx.x;
    wf[i] = (_Float16)(w[i] * 1024.0f);
}

// ---- P2: pack z -> fp16 [65536 pix][256 k] (LDS transpose) -----------------
__global__ __launch_bounds__(256) void zpack_kernel(const float* __restrict__ z,
                                                    _Float16* __restrict__ zf) {
    __shared__ float zs[64 * 65];
    const int t = threadIdx.x;
    const int P0 = blockIdx.x * 64;
    const int b = P0 >> 12, hw0 = P0 & (NHW - 1);
    const int K0 = blockIdx.y * 64;
    const int hw = t & 63, cq = t >> 6;
    const float* zb = z + (size_t)b * (NC * NHW) + hw0 + hw;
    #pragma unroll
    for (int i = 0; i < 16; ++i) {
        int kl = cq * 16 + i;
        zs[hw * 65 + kl] = zb[(size_t)(K0 + kl) * NHW];
    }
    __syncthreads();
    const int p = t >> 2, kq = t & 3;
    size_t obase = (size_t)(P0 + p) * NC + K0 + kq * 16;
    #pragma unroll
    for (int h2 = 0; h2 < 2; ++h2) {
        half8 v;
        #pragma unroll
        for (int j2 = 0; j2 < 8; ++j2)
            v[j2] = (_Float16)zs[p * 65 + kq * 16 + h2 * 8 + j2];
        *(half8*)&zf[obase + h2 * 8] = v;
    }
}

// ---- K1: fp16 MFMA GEMM, BARRIER-FREE main loop (w direct to VGPR) ---------
// z tile persistent in LDS; w fragments loaded per-wave global->register with
// one-step-ahead ping-pong prefetch. No __syncthreads between k-steps.
__global__ __launch_bounds__(512) void gemm2_kernel(const _Float16* __restrict__ wf,
                                                    const _Float16* __restrict__ zf,
                                                    const float* __restrict__ wsum,
                                                    float* __restrict__ idxf,
                                                    int* __restrict__ idxi,
                                                    ushort_t* __restrict__ list,
                                                    int* __restrict__ cnt,
                                                    float* __restrict__ ncs,
                                                    int* __restrict__ ccount) {
    __shared__ __align__(16) _Float16 zt[256 * 256];  // 128 KB, persistent
    __shared__ float bvx[512], svx[512];
    __shared__ int   bix[512];
    __shared__ int   h[NE];

    const int t = threadIdx.x;
    const int l = t & 63;
    const int w = t >> 6;                             // 0..7
    const int P0 = blockIdx.x * 256;
    const int wc = w >> 2;                            // code half 0..1
    const int wp = w & 3;                             // px quarter 0..3

    // persistent z stage: LDS(row,chunk) = global(row, chunk ^ (row&7))
    #pragma unroll
    for (int i = 0; i < 16; ++i) {
        int row = w * 32 + i * 2 + (l >> 5);
        int gc = (l & 31) ^ (row & 7);
        gload16(zf + (size_t)(P0 + row) * NC + gc * 8,
                &zt[w * 8192 + i * 512 + l * 8]);
    }

    // per-lane w base: rows wc*64 + m*16 + (l&15), k-chunk (l>>4)*8
    const _Float16* wbase = wf + ((wc * 64 + (l & 15)) * 256 + (l >> 4) * 8);
    int bbase[4], bx32[4];
    #pragma unroll
    for (int n = 0; n < 4; ++n) {
        int row = wp * 64 + n * 16 + (l & 15);
        int r3 = row & 7;
        bbase[n] = row * 256 + (((l >> 4) ^ (r3 & 3)) * 8);
        bx32[n] = (r3 >> 2) * 32;
    }

    half8 aA[4], aB[4];
    #pragma unroll
    for (int m = 0; m < 4; ++m) aA[m] = *(const half8*)(wbase + m * 4096);

    float rbv2[4], rsv2[4];
    int   rbi2[4];
    #pragma unroll
    for (int n = 0; n < 4; ++n) { rbv2[n] = 3.4e38f; rsv2[n] = 3.4e38f; rbi2[n] = 0; }

    __syncthreads();                                  // zt ready (only loop barrier)

    #pragma unroll 1
    for (int ct = 0; ct < 8; ++ct) {
        const _Float16* wct = wbase + ct * 32768;
        f32x4 acc[4][4];
        #pragma unroll
        for (int m = 0; m < 4; ++m)
            #pragma unroll
            for (int n = 0; n < 4; ++n)
                #pragma unroll
                for (int e = 0; e < 4; ++e) acc[m][n][e] = 0.0f;

        #pragma unroll
        for (int kp = 0; kp < 4; ++kp) {
            {   // step 2*kp: consume aA, prefetch aB (step 2*kp+1)
                const _Float16* nsrc = wct + (2 * kp + 1) * 32;
                #pragma unroll
                for (int m = 0; m < 4; ++m) aB[m] = *(const half8*)(nsrc + m * 4096);
                __builtin_amdgcn_s_setprio(1);
                half8 b[4];
                #pragma unroll
                for (int n = 0; n < 4; ++n)
                    b[n] = *(const half8*)&zt[bbase[n] + (((2 * kp) * 32) ^ bx32[n])];
                #pragma unroll
                for (int m = 0; m < 4; ++m)
                    #pragma unroll
                    for (int n = 0; n < 4; ++n)
                        acc[m][n] = __builtin_amdgcn_mfma_f32_16x16x32_f16(aA[m], b[n], acc[m][n], 0, 0, 0);
                __builtin_amdgcn_s_setprio(0);
            }
            {   // step 2*kp+1: consume aB, prefetch aA (next step / next ct)
                if (ct < 7 || kp < 3) {
                    const _Float16* nsrc = (kp < 3) ? (wct + (2 * kp + 2) * 32)
                                                    : (wct + 32768);
                    #pragma unroll
                    for (int m = 0; m < 4; ++m) aA[m] = *(const half8*)(nsrc + m * 4096);
                }
                __builtin_amdgcn_s_setprio(1);
                half8 b[4];
                #pragma unroll
                for (int n = 0; n < 4; ++n)
                    b[n] = *(const half8*)&zt[bbase[n] + (((2 * kp + 1) * 32) ^ bx32[n])];
                #pragma unroll
                for (int m = 0; m < 4; ++m)
                    #pragma unroll
                    for (int n = 0; n < 4; ++n)
                        acc[m][n] = __builtin_amdgcn_mfma_f32_16x16x32_f16(aB[m], b[n], acc[m][n], 0, 0, 0);
                __builtin_amdgcn_s_setprio(0);
            }
        }

        // fold into running in-lane top-2 (registers only)
        #pragma unroll
        for (int m = 0; m < 4; ++m) {
            float4 env = *(const float4*)&wsum[ct * 128 + wc * 64 + m * 16 + (l >> 4) * 4];
            const float* en = &env.x;
            #pragma unroll
            for (int n = 0; n < 4; ++n)
                #pragma unroll
                for (int r = 0; r < 4; ++r) {
                    float s = en[r] - acc[m][n][r] * 0.001953125f;  // 2^-9
                    int code = ct * 128 + wc * 64 + m * 16 + (l >> 4) * 4 + r;
                    if (s < rbv2[n]) { rsv2[n] = rbv2[n]; rbv2[n] = s; rbi2[n] = code; }
                    else if (s < rsv2[n]) rsv2[n] = s;  // codes ascend in-lane
                }
        }
    }

    // final cross-lane reduce per n
    #pragma unroll
    for (int n = 0; n < 4; ++n) {
        float bv = rbv2[n], sv = rsv2[n];
        int bi = rbi2[n];
        #pragma unroll
        for (int x = 16; x <= 32; x <<= 1) {
            float v2 = __shfl_xor(bv, x);
            float s2 = __shfl_xor(sv, x);
            int   i2 = __shfl_xor(bi, x);
            if (v2 < bv || (v2 == bv && i2 < bi)) { sv = fminf(bv, s2); bv = v2; bi = i2; }
            else sv = fminf(sv, v2);
        }
        if ((l >> 4) == 0) {
            int lp = wp * 64 + n * 16 + l;
            bvx[wc * 256 + lp] = bv;
            svx[wc * 256 + lp] = sv;
            bix[wc * 256 + lp] = bi;
        }
    }
    h[t] = 0;
    h[t + 512] = 0;
    __syncthreads();
    if (t < 256) {                                    // merge the two code-halves
        float bv = bvx[t], sv = svx[t];
        int bi = bix[t];
        float v2 = bvx[256 + t], s2 = svx[256 + t];
        int i2 = bix[256 + t];
        if (v2 < bv || (v2 == bv && i2 < bi)) { sv = fminf(bv, s2); bv = v2; bi = i2; }
        else sv = fminf(sv, v2);
        int pix = P0 + t;
        idxf[pix] = (float)bi;
        idxi[pix] = bi;
        atomicAdd(&h[bi], 1);
        if (sv - bv < GAP_FLAG) {
            int pos = atomicAdd(cnt, 1);
            list[pos] = (ushort_t)pix;
        }
    }
    __syncthreads();
    {
        int v = h[t];
        if (v) { atomicAdd(&ncs[t], (float)v); atomicAdd(&ccount[t], v); }
        v = h[t + 512];
        if (v) { atomicAdd(&ncs[t + 512], (float)v); atomicAdd(&ccount[t + 512], v); }
    }
}

// ================== FALLBACK PATH (round-7 argmin), used if ws too small ====
__global__ __launch_bounds__(256) void argmin_kernel(const float* __restrict__ z,
                                                     const float* __restrict__ w,
                                                     const float* __restrict__ enorm,
                                                     float* __restrict__ idxf,
                                                     int* __restrict__ idxi,
                                                     unsigned long long* __restrict__ flags) {
    __shared__ __align__(16) float smem[64 * 68 + 128 * 68];
    float* zt = smem;
    float* wt = smem + 64 * 68;
    const int t = threadIdx.x;
    const int pr = t & 7;
    const int cr = t >> 3;
    const int P0 = blockIdx.x * 64;
    const int b = P0 >> 12;
    const int hw0 = P0 & (NHW - 1);
    const float* zb = z + (size_t)b * (NC * NHW) + hw0;
    float bestv[8], secv[8];
    int besti[8];
    #pragma unroll
    for (int i = 0; i < 8; ++i) { bestv[i] = 3.4e38f; secv[i] = 3.4e38f; besti[i] = 0; }
    for (int cc = 0; cc < 8; ++cc) {
        float acc[8][4];
        #pragma unroll
        for (int i = 0; i < 8; ++i)
            #pragma unroll
            for (int j = 0; j < 4; ++j) acc[i][j] = 0.0f;
        for (int kc = 0; kc < 4; ++kc) {
            {
                int p = t & 63;
                int k0 = (t >> 6) * 16;
                int f2 = ((p >> 3) & 3) << 2;
                #pragma unroll
                for (int i = 0; i < 16; ++i) {
                    int k = k0 + i;
                    zt[p * 68 + (k ^ f2)] = zb[(size_t)(kc * 64 + k) * NHW + p];
                }
            }
            {
                #pragma unroll
                for (int i = 0; i < 8; ++i) {
                    int f = t + 256 * i;
                    int jj = f >> 4;
                    int k4 = f & 15;
                    float4 v = *(const float4*)&w[(size_t)(cc * 128 + jj) * NC + kc * 64 + k4 * 4];
                    *(float4*)&wt[jj * 68 + k4 * 4] = v;
                }
            }
            __syncthreads();
            #pragma unroll 2
            for (int k = 0; k < 64; k += 4) {
                float4 za[8], wb[4];
                #pragma unroll
                for (int i = 0; i < 8; ++i)
                    za[i] = *(float4*)&zt[(pr + 8 * i) * 68 + (k ^ ((i & 3) << 2))];
                #pragma unroll
                for (int j = 0; j < 4; ++j)
                    wb[j] = *(float4*)&wt[(cr + 32 * j) * 68 + k];
                #pragma unroll
                for (int i = 0; i < 8; ++i)
                    #pragma unroll
                    for (int j = 0; j < 4; ++j)
                        acc[i][j] += za[i].x * wb[j].x + za[i].y * wb[j].y +
                                     za[i].z * wb[j].z + za[i].w * wb[j].w;
            }
            __syncthreads();
        }
        #pragma unroll
        for (int j = 0; j < 4; ++j) {
            int code = cc * 128 + cr + 32 * j;
            float enj = enorm[code];
            #pragma unroll
            for (int i = 0; i < 8; ++i) {
                float s = enj - 2.0f * acc[i][j];
                if (s < bestv[i]) { secv[i] = bestv[i]; bestv[i] = s; besti[i] = code; }
                else if (s < secv[i]) secv[i] = s;
            }
        }
    }
    float* rv = smem;
    int* ri = (int*)(smem + 2048);
    float* rs = smem + 4096;
    #pragma unroll
    for (int i = 0; i < 8; ++i) {
        int p = pr + 8 * i;
        rv[p * 32 + cr] = bestv[i];
        ri[p * 32 + cr] = besti[i];
        rs[p * 32 + cr] = secv[i];
    }
    __syncthreads();
    if (t < 64) {
        int p = t;
        float bv = rv[p * 32], sv = rs[p * 32];
        int bi = ri[p * 32];
        for (int s2 = 1; s2 < 32; ++s2) {
            float v = rv[p * 32 + s2];
            float v2 = rs[p * 32 + s2];
            int ii = ri[p * 32 + s2];
            if (v < bv) { sv = bv; bv = v; bi = ii; }
            else {
                if (v < sv) sv = v;
                if (v == bv && ii < bi) bi = ii;
            }
            if (v2 < sv) sv = v2;
        }
        idxf[P0 + p] = (float)bi;
        idxi[P0 + p] = bi;
        unsigned long long mask = __ballot((sv - bv) < GAP_FLAG);
        if (t == 0) flags[blockIdx.x] = mask;
    }
}

__global__ __launch_bounds__(256) void gather_kernel(const unsigned long long* __restrict__ flags,
                                                     ushort_t* __restrict__ list,
                                                     int* __restrict__ cnt) {
    int p = blockIdx.x * 256 + threadIdx.x;
    unsigned long long m = flags[p >> 6];
    if ((m >> (p & 63)) & 1ULL) {
        int pos = atomicAdd(cnt, 1);
        list[pos] = (ushort_t)p;
    }
}

__global__ __launch_bounds__(1024) void hist_kernel(const int* __restrict__ idxi,
                                                    float* __restrict__ ncs) {
    __shared__ int h[NE];
    int t = threadIdx.x;
    h[t] = 0;
    __syncthreads();
    int gid = blockIdx.x * 1024 + t;
    #pragma unroll
    for (int i = 0; i < 4; ++i) atomicAdd(&h[idxi[gid + i * 16384]], 1);
    __syncthreads();
    if (h[t]) atomicAdd(&ncs[t], (float)h[t]);
}

__global__ __launch_bounds__(1024, 8) void dwloss_kernel(const float* __restrict__ z,
                                                         const float* __restrict__ w,
                                                         const int* __restrict__ idxi,
                                                         float* __restrict__ dw0,
                                                         float* __restrict__ dw1,
                                                         float* __restrict__ lpart) {
    __shared__ float acc[NE];
    __shared__ float wcol[NE];
    __shared__ float ls[16];
    const int c = blockIdx.x;
    const int part = blockIdx.y;
    const int t = threadIdx.x;
    acc[t] = 0.0f;
    wcol[t] = w[(size_t)t * NC + c];
    __syncthreads();
    const float* zc = z + (size_t)c * NHW;
    float lsum = 0.0f;
    #pragma unroll
    for (int half = 0; half < 2; ++half) {
        float4 zv[4];
        int4   iv[4];
        #pragma unroll
        for (int i = 0; i < 4; ++i) {
            int b = part * 8 + half * 4 + i;
            zv[i] = *(const float4*)&zc[(size_t)b * (NC * NHW) + t * 4];
            iv[i] = *(const int4*)&idxi[b * 4096 + t * 4];
        }
        #pragma unroll
        for (int i = 0; i < 4; ++i) {
            float q0 = wcol[iv[i].x], q1 = wcol[iv[i].y];
            float q2 = wcol[iv[i].z], q3 = wcol[iv[i].w];
            float d0 = q0 - zv[i].x, d1 = q1 - zv[i].y;
            float d2 = q2 - zv[i].z, d3 = q3 - zv[i].w;
            lsum += d0 * d0 + d1 * d1 + d2 * d2 + d3 * d3;
            atomicAdd(&acc[iv[i].x], zv[i].x);
            atomicAdd(&acc[iv[i].y], zv[i].y);
            atomicAdd(&acc[iv[i].z], zv[i].z);
            atomicAdd(&acc[iv[i].w], zv[i].w);
        }
    }
    #pragma unroll
    for (int off = 32; off > 0; off >>= 1) lsum += __shfl_down(lsum, off);
    if ((t & 63) == 0) ls[t >> 6] = lsum;
    __syncthreads();
    if (t == 0) {
        float s = 0.0f;
        #pragma unroll
        for (int q = 0; q < 16; ++q) s += ls[q];
        lpart[c * 2 + part] = s;
    }
    float* dwp = part ? dw1 : dw0;
    dwp[(size_t)t * NC + c] = acc[t];
}
// ================== end fallback ============================================

// ---- K1b: np-fp32-mimic re-argmin, 8 flagged pixels per block --------------
__global__ __launch_bounds__(256) void fixup3_kernel(const float* __restrict__ z,
                                                     const float* __restrict__ w,
                                                     const float* __restrict__ wsum,
                                                     const ushort_t* __restrict__ list,
                                                     const int* __restrict__ cnt,
                                                     float* __restrict__ idxf,
                                                     int* __restrict__ idxi,
                                                     float* __restrict__ ncs,
                                                     int* __restrict__ ccount) {
    const int count = cnt[0];
    if (count == 0) return;
    const int ngroups = (count + 7) >> 3;
    const int t = threadIdx.x;

    __shared__ __align__(16) char smem_raw[16384 + 8192];
    double (*zd)[NC] = (double(*)[NC])smem_raw;
    float  (*zf)[NC] = (float(*)[NC])(smem_raw + 16384);
    float* rbv = (float*)(smem_raw + 16384);
    int*   rbi = (int*)smem_raw;
    __shared__ float zs_sh[8];
    __shared__ int   pix_sh[8];
    __shared__ float r2v[8][32];
    __shared__ int   r2i[8][32];

    for (int g = blockIdx.x; g < ngroups; g += gridDim.x) {
        if (t < 8) {
            int i = g * 8 + t;
            pix_sh[t] = (i < count) ? (int)list[i] : (int)list[0];
        }
        __syncthreads();
        #pragma unroll
        for (int px = 0; px < 8; ++px) {
            int p = pix_sh[px];
            int b = p >> 12, hw = p & (NHW - 1);
            float zv = z[(size_t)b * (NC * NHW) + (size_t)t * NHW + hw];
            zf[px][t] = zv;
            zd[px][t] = (double)zv;
        }
        __syncthreads();
        if (t < 8) zs_sh[t] = np_pair128_sq(zf[t]) + np_pair128_sq(zf[t] + 128);
        __syncthreads();

        float zs_reg[8];
        #pragma unroll
        for (int px = 0; px < 8; ++px) zs_reg[px] = zs_sh[px];

        float bvr[8];
        int   bir[8];
        #pragma unroll
        for (int px = 0; px < 8; ++px) { bvr[px] = 3.4e38f; bir[px] = 0; }

        #pragma unroll
        for (int jo = 0; jo < 2; ++jo) {
            const int j0 = t + jo * 512;
            const int j1 = j0 + 256;
            const float* wr0 = w + (size_t)j0 * NC;
            const float* wr1 = w + (size_t)j1 * NC;
            double acc0[8], acc1[8];
            #pragma unroll
            for (int px = 0; px < 8; ++px) { acc0[px] = 0.0; acc1[px] = 0.0; }
            for (int k = 0; k < NC; k += 4) {
                float4 wa = *(const float4*)&wr0[k];
                float4 wb = *(const float4*)&wr1[k];
                const float* wap = (const float*)&wa;
                const float* wbp = (const float*)&wb;
                #pragma unroll
                for (int e = 0; e < 4; ++e) {
                    double wea = (double)wap[e];
                    double web = (double)wbp[e];
                    #pragma unroll
                    for (int px = 0; px < 8; ++px) {
                        double zv = zd[px][k + e];
                        acc0[px] += wea * zv;
                        acc1[px] += web * zv;
                    }
                }
            }
            float ws0 = wsum[j0], ws1 = wsum[j1];
            #pragma unroll
            for (int px = 0; px < 8; ++px) {
                float m0 = (float)acc0[px];
                float s10 = zs_reg[px] + ws0;
                float d0 = s10 - 2.0f * m0;
                if (d0 < bvr[px] || (d0 == bvr[px] && j0 < bir[px])) { bvr[px] = d0; bir[px] = j0; }
                float m1 = (float)acc1[px];
                float s11 = zs_reg[px] + ws1;
                float d1 = s11 - 2.0f * m1;
                if (d1 < bvr[px] || (d1 == bvr[px] && j1 < bir[px])) { bvr[px] = d1; bir[px] = j1; }
            }
        }
        __syncthreads();
        #pragma unroll
        for (int px = 0; px < 8; ++px) {
            rbv[px * 256 + t] = bvr[px];
            rbi[px * 256 + t] = bir[px];
        }
        __syncthreads();
        {
            int px = t >> 5, s = t & 31;
            float bv = rbv[px * 256 + s * 8];
            int   bi = rbi[px * 256 + s * 8];
            #pragma unroll
            for (int e = 1; e < 8; ++e) {
                float v2 = rbv[px * 256 + s * 8 + e];
                int   i2 = rbi[px * 256 + s * 8 + e];
                if (v2 < bv || (v2 == bv && i2 < bi)) { bv = v2; bi = i2; }
            }
            r2v[px][s] = bv;
            r2i[px][s] = bi;
        }
        __syncthreads();
        if (t < 8) {
            float bv = r2v[t][0];
            int   bi = r2i[t][0];
            for (int s = 1; s < 32; ++s) {
                float v2 = r2v[t][s];
                int   i2 = r2i[t][s];
                if (v2 < bv || (v2 == bv && i2 < bi)) { bv = v2; bi = i2; }
            }
            if (g * 8 + t < count) {
                int p = pix_sh[t];
                int old = idxi[p];
                if (old != bi) {
                    idxf[p] = (float)bi;
                    idxi[p] = bi;
                    atomicAdd(&ncs[old], -1.0f);
                    atomicAdd(&ncs[bi], 1.0f);
                    if (ccount) {
                        atomicAdd(&ccount[old], -1);
                        atomicAdd(&ccount[bi], 1);
                    }
                }
            }
        }
        __syncthreads();
    }
}

// ---- K2b: out write only (no z): gather wcol[id] -> out --------------------
__global__ __launch_bounds__(1024, 8) void out2_kernel(const float* __restrict__ w,
                                                       const int* __restrict__ idxi,
                                                       float* __restrict__ outq) {
    __shared__ float wcol[NE];
    const int c = blockIdx.x;
    const int part = blockIdx.y;
    const int t = threadIdx.x;
    wcol[t] = w[(size_t)t * NC + c];
    __syncthreads();
    float* oc = outq + (size_t)c * NHW;
    #pragma unroll
    for (int half = 0; half < 2; ++half) {
        int4 iv[4];
        #pragma unroll
        for (int i = 0; i < 4; ++i) {
            int b = part * 8 + half * 4 + i;
            iv[i] = *(const int4*)&idxi[b * 4096 + t * 4];
        }
        asm volatile("" :: "v"(iv[0].x), "v"(iv[1].x), "v"(iv[2].x), "v"(iv[3].x));
        #pragma unroll
        for (int i = 0; i < 4; ++i) {
            int b = part * 8 + half * 4 + i;
            float4 ov;
            ov.x = wcol[iv[i].x]; ov.y = wcol[iv[i].y];
            ov.z = wcol[iv[i].z]; ov.w = wcol[iv[i].w];
            *(float4*)&oc[(size_t)b * (NC * NHW) + t * 4] = ov;
        }
    }
}

// ---- K2c-1: exclusive prefix scan of per-code counts -----------------------
__global__ __launch_bounds__(1024) void scan_kernel(const int* __restrict__ ccount,
                                                    int* __restrict__ offs,
                                                    int* __restrict__ cur) {
    __shared__ int s[1024];
    int t = threadIdx.x;
    int c0 = ccount[t];
    s[t] = c0;
    __syncthreads();
    for (int off = 1; off < 1024; off <<= 1) {
        int v = (t >= off) ? s[t - off] : 0;
        __syncthreads();
        s[t] += v;
        __syncthreads();
    }
    int ex = s[t] - c0;
    offs[t] = ex;
    cur[t] = ex;
}

// ---- K2c-2: counting-sort scatter: pixels grouped by code ------------------
__global__ __launch_bounds__(256) void scatter2_kernel(const int* __restrict__ idxi,
                                                       int* __restrict__ cur,
                                                       int* __restrict__ sorted) {
    int p = blockIdx.x * 256 + threadIdx.x;
    int id = idxi[p];
    int pos = atomicAdd(&cur[id], 1);
    sorted[pos] = p;
}

// ---- K2c-3: dense segmented dw sum + loss; one wave per (code, half) -------
__global__ __launch_bounds__(256) void dwsum2_kernel(const _Float16* __restrict__ zf,
                                                     const float* __restrict__ w,
                                                     const int* __restrict__ sorted,
                                                     const int* __restrict__ offs,
                                                     const int* __restrict__ ccount,
                                                     float* __restrict__ dw0,
                                                     float* __restrict__ dw1,
                                                     float* __restrict__ lpart) {
    const int t = threadIdx.x, l = t & 63, wv = t >> 6;
    const int j = blockIdx.x * 4 + wv;               // code
    const int part = blockIdx.y;                     // half of this code's list
    const float4 q = *(const float4*)&w[(size_t)j * NC + l * 4];
    const int start = offs[j], cntj = ccount[j];
    const int h0 = (cntj + 1) >> 1;
    const int s = part ? start + h0 : start;
    const int e = part ? start + cntj : start + h0;
    float a0 = 0.f, a1 = 0.f, a2 = 0.f, a3 = 0.f, lsum = 0.f;
    for (int base = s; base < e; base += 64) {
        int pm = (base + l < e) ? sorted[base + l] : 0;
        int nn = min(64, e - base);
        for (int i = 0; i < nn; ++i) {
            int p = __shfl(pm, i);                   // broadcast pixel id
            half4 zv = *(const half4*)&zf[(size_t)p * NC + l * 4];
            float z0 = (float)zv[0], z1 = (float)zv[1];
            float z2 = (float)zv[2], z3 = (float)zv[3];
            a0 += z0; a1 += z1; a2 += z2; a3 += z3;
            float d0 = q.x - z0, d1 = q.y - z1, d2 = q.z - z2, d3 = q.w - z3;
            lsum += d0 * d0 + d1 * d1 + d2 * d2 + d3 * d3;
        }
    }
    float* dwp = part ? dw1 : dw0;
    float4 av = make_float4(a0, a1, a2, a3);
    *(float4*)&dwp[(size_t)j * NC + l * 4] = av;
    #pragma unroll
    for (int off = 32; off > 0; off >>= 1) lsum += __shfl_down(lsum, off);
    if (l == 0) lpart[j * 2 + part] = lsum;
}

// ---- K3: finalize (2048 loss partials) -------------------------------------
__global__ __launch_bounds__(1024) void finalize_kernel(const float* __restrict__ cs,
                                                        const float* __restrict__ lpart,
                                                        float* __restrict__ ncs,
                                                        float* __restrict__ cssm,
                                                        float* __restrict__ loss) {
    int t = threadIdx.x;
    float cnt = ncs[t];
    float v = cs[t] * DECAY + (1.0f - DECAY) * cnt;
    ncs[t] = v;
    __shared__ float red[1024];
    red[t] = v;
    __syncthreads();
    for (int s = 512; s > 0; s >>= 1) {
        if (t < s) red[t] += red[t + s];
        __syncthreads();
    }
    float n = red[0];
    __syncthreads();
    cssm[t] = (v + EPS_) / (n + (float)NE * EPS_) * n;
    red[t] = lpart[t] + lpart[t + 1024];
    __syncthreads();
    for (int s = 512; s > 0; s >>= 1) {
        if (t < s) red[t] += red[t + s];
        __syncthreads();
    }
    if (t == 0) loss[0] = BETA * red[0] / 16777216.0f;
}

// ---- K4: nea + new_weight in-place (nea/nw currently hold dw partials) -----
__global__ __launch_bounds__(256) void neaw_kernel(const float* __restrict__ ea,
                                                   const float* __restrict__ cssm,
                                                   float* __restrict__ nea,
                                                   float* __restrict__ nw) {
    int lin = blockIdx.x * 256 + threadIdx.x;
    float dw = nea[lin] + nw[lin];
    float v = DECAY * ea[lin] + (1.0f - DECAY) * dw;
    nea[lin] = v;
    nw[lin] = v / cssm[lin >> 8];
}

extern "C" void kernel_launch(void* const* d_in, const int* in_sizes, int n_in,
                              void* d_out, int out_size, void* d_ws, size_t ws_size,
                              hipStream_t stream) {
    const float* z  = (const float*)d_in[0];
    const float* w  = (const float*)d_in[1];
    const float* cs = (const float*)d_in[2];
    const float* ea = (const float*)d_in[3];

    float* out  = (float*)d_out;
    float* loss = out + OFF_LOSS;
    float* idxf = out + OFF_IDXF;
    float* ncs  = out + OFF_NCS;
    float* nea  = out + OFF_NEA;
    float* nw   = out + OFF_NW;

    float* wsf = (float*)d_ws;
    float* wsum = wsf + WS_WSUM;
    float* cssm = wsf + WS_CSSM;
    float* lpart = wsf + WS_LPART;
    int* cnt = (int*)(wsf + WS_CNT);
    unsigned long long* flags = (unsigned long long*)(wsf + WS_FLAGS);
    ushort_t* list = (ushort_t*)(wsf + WS_LIST);
    int* idxi = (int*)(wsf + WS_IDXI);
    int* ccount = (int*)(wsf + WS_CCNT);
    int* offs = (int*)(wsf + WS_OFFS);
    int* cur = (int*)(wsf + WS_CUR);
    int* sorted = (int*)(wsf + WS_SORT);

    const bool fast = ws_size >= (size_t)WS_END * 4;

    hipLaunchKernelGGL(wsum_kernel, dim3(16), dim3(64), 0, stream, w, wsum, ncs, cnt,
                       fast ? ccount : cnt, lpart);

    if (fast) {
        _Float16* wf16 = (_Float16*)(wsf + WS_WF16);
        _Float16* zf16 = (_Float16*)(wsf + WS_ZF16);
        hipLaunchKernelGGL(wpack_kernel, dim3(1024), dim3(256), 0, stream, w, wf16);
        hipLaunchKernelGGL(zpack_kernel, dim3(1024, 4), dim3(256), 0, stream, z, zf16);
        hipLaunchKernelGGL(gemm2_kernel, dim3(256), dim3(512), 0, stream,
                           wf16, zf16, wsum, idxf, idxi, list, cnt, ncs, ccount);
        hipLaunchKernelGGL(fixup3_kernel, dim3(256), dim3(256), 0, stream,
                           z, w, wsum, list, cnt, idxf, idxi, ncs, ccount);
        hipLaunchKernelGGL(out2_kernel, dim3(256, 2), dim3(1024), 0, stream, w, idxi, out);
        hipLaunchKernelGGL(scan_kernel, dim3(1), dim3(1024), 0, stream, ccount, offs, cur);
        hipLaunchKernelGGL(scatter2_kernel, dim3(256), dim3(256), 0, stream, idxi, cur, sorted);
        hipLaunchKernelGGL(dwsum2_kernel, dim3(256, 2), dim3(256), 0, stream,
                           zf16, w, sorted, offs, ccount, nea, nw, lpart);
    } else {
        hipLaunchKernelGGL(argmin_kernel, dim3(1024), dim3(256), 0, stream, z, w, wsum, idxf, idxi, flags);
        hipLaunchKernelGGL(gather_kernel, dim3(256), dim3(256), 0, stream, flags, list, cnt);
        hipLaunchKernelGGL(hist_kernel, dim3(16), dim3(1024), 0, stream, idxi, ncs);
        hipLaunchKernelGGL(fixup3_kernel, dim3(256), dim3(256), 0, stream,
                           z, w, wsum, list, cnt, idxf, idxi, ncs, (int*)nullptr);
        hipLaunchKernelGGL(out2_kernel, dim3(256, 2), dim3(1024), 0, stream, w, idxi, out);
        hipLaunchKernelGGL(dwloss_kernel, dim3(256, 2), dim3(1024), 0, stream, z, w, idxi, nea, nw, lpart);
    }

    hipLaunchKernelGGL(finalize_kernel, dim3(1), dim3(1024), 0, stream, cs, lpart, ncs, cssm, loss);
    hipLaunchKernelGGL(neaw_kernel, dim3(1024), dim3(256), 0, stream, ea, cssm, nea, nw);
}

// Round 20
// 260.167 us; speedup vs baseline: 1.0886x; 1.0886x over previous
//
#include <hip/hip_runtime.h>
#include <hip/hip_bf16.h>

typedef unsigned short ushort_t;
typedef __attribute__((ext_vector_type(8))) _Float16 half8;
typedef __attribute__((ext_vector_type(4))) _Float16 half4;
typedef __attribute__((ext_vector_type(4))) float f32x4;

// Problem constants
#define NB    16
#define NC    256
#define NHW   4096
#define NPIX  65536
#define NE    1024
#define BETA  0.25f
#define DECAY 0.99f
#define EPS_  1e-5f
#define GAP_FLAG 1.25e-4f

// d_out layout (floats)
#define OFF_LOSS 16777216
#define OFF_IDXF 16777217
#define OFF_NCS  16842753
#define OFF_NEA  16843777
#define OFF_NW   17105921

// ws layout (float offsets)
#define WS_WSUM  0
#define WS_CSSM  1024
#define WS_LPART 2048                     // 2048 floats (per-code,2 parts)
#define WS_CNT   4096
#define WS_FLAGS 4128
#define WS_LIST  6176                     // 65536 u16 = 32768 floats
#define WS_WF16  40960                    // 1024*256 fp16
#define WS_ZF16  (WS_WF16 + 131072)       // 65536*256 fp16
#define WS_IDXI  (WS_ZF16 + 8388608)      // 65536 int
#define WS_CCNT  (WS_IDXI + 65536)        // 1024 int
#define WS_OFFS  (WS_CCNT + 1024)         // 1024 int
#define WS_CUR   (WS_OFFS + 1024)         // 1024 int
#define WS_SORT  (WS_CUR + 1024)          // 65536 int
#define WS_END   (WS_SORT + 65536)

__device__ __forceinline__ float sq_nofma(float x) {
    float s = x * x;
    asm volatile("" : "+v"(s));
    return s;
}

__device__ __forceinline__ float np_pair128_sq(const float* __restrict__ a) {
    float r[8];
    #pragma unroll
    for (int m = 0; m < 8; ++m) r[m] = sq_nofma(a[m]);
    for (int i = 8; i < 128; i += 8) {
        #pragma unroll
        for (int m = 0; m < 8; ++m) r[m] += sq_nofma(a[i + m]);
    }
    return ((r[0] + r[1]) + (r[2] + r[3])) + ((r[4] + r[5]) + (r[6] + r[7]));
}

__device__ __forceinline__ void gload16(const void* g, void* ldsp) {
    __builtin_amdgcn_global_load_lds((const __attribute__((address_space(1))) unsigned int*)g,
                                     (__attribute__((address_space(3))) unsigned int*)ldsp,
                                     16, 0, 0);
}

// ---- K0b: wsum + init of ncs/cnt/ccount/lpart ------------------------------
__global__ __launch_bounds__(64) void wsum_kernel(const float* __restrict__ w,
                                                  float* __restrict__ wsum,
                                                  float* __restrict__ ncs,
                                                  int* __restrict__ cnt,
                                                  int* __restrict__ ccount,
                                                  float* __restrict__ lpart) {
    int j = blockIdx.x * 64 + threadIdx.x;
    const float* wr = w + (size_t)j * NC;
    wsum[j] = np_pair128_sq(wr) + np_pair128_sq(wr + 128);
    ncs[j] = 0.0f;
    ccount[j] = 0;
    lpart[j] = 0.0f;
    lpart[j + 1024] = 0.0f;
    if (j == 0) cnt[0] = 0;
}

// ---- P1: pack w -> fp16, scaled by 1024 ------------------------------------
__global__ __launch_bounds__(256) void wpack_kernel(const float* __restrict__ w,
                                                    _Float16* __restrict__ wf) {
    int i = blockIdx.x * 256 + threadIdx.x;
    wf[i] = (_Float16)(w[i] * 1024.0f);
}

// ---- P2: pack z -> fp16 [65536 pix][256 k] (LDS transpose) -----------------
__global__ __launch_bounds__(256) void zpack_kernel(const float* __restrict__ z,
                                                    _Float16* __restrict__ zf) {
    __shared__ float zs[64 * 65];
    const int t = threadIdx.x;
    const int P0 = blockIdx.x * 64;
    const int b = P0 >> 12, hw0 = P0 & (NHW - 1);
    const int K0 = blockIdx.y * 64;
    const int hw = t & 63, cq = t >> 6;
    const float* zb = z + (size_t)b * (NC * NHW) + hw0 + hw;
    #pragma unroll
    for (int i = 0; i < 16; ++i) {
        int kl = cq * 16 + i;
        zs[hw * 65 + kl] = zb[(size_t)(K0 + kl) * NHW];
    }
    __syncthreads();
    const int p = t >> 2, kq = t & 3;
    size_t obase = (size_t)(P0 + p) * NC + K0 + kq * 16;
    #pragma unroll
    for (int h2 = 0; h2 < 2; ++h2) {
        half8 v;
        #pragma unroll
        for (int j2 = 0; j2 < 8; ++j2)
            v[j2] = (_Float16)zs[p * 65 + kq * 16 + h2 * 8 + j2];
        *(half8*)&zf[obase + h2 * 8] = v;
    }
}

// ---- K1: fp16 MFMA GEMM, quad-buffered wt, counted-vmcnt raw barriers ------
// T4: stage next step's w, s_waitcnt vmcnt(1) (own prior stage landed), raw
// s_barrier (no drain). buf = ks&3; readers of a buffer are >=2 barriers away
// from its next writer -> race-free. Loads stay in flight across barriers.
__global__ __launch_bounds__(512) void gemm2_kernel(const _Float16* __restrict__ wf,
                                                    const _Float16* __restrict__ zf,
                                                    const float* __restrict__ wsum,
                                                    float* __restrict__ idxf,
                                                    int* __restrict__ idxi,
                                                    ushort_t* __restrict__ list,
                                                    int* __restrict__ cnt,
                                                    float* __restrict__ ncs,
                                                    int* __restrict__ ccount) {
    __shared__ __align__(16) char smem[163840];       // 128K zt | 4x8K wt
    _Float16* zt = (_Float16*)smem;
    _Float16* wt = (_Float16*)(smem + 131072);
    float* bvx = (float*)(smem + 131072);             // alias wt (post-barrier)
    float* svx = bvx + 512;
    int*   bix = (int*)(svx + 512);
    int*   h   = (int*)smem;                          // alias zt (post-barrier)

    const int t = threadIdx.x;
    const int l = t & 63;
    const int w = t >> 6;                             // 0..7
    const int P0 = blockIdx.x * 256;
    const int wc = w >> 2;                            // code half 0..1
    const int wp = w & 3;                             // px quarter 0..3

    // hoisted per-lane addresses (fp16-element units)
    const int sdest = w * 512 + l * 8;                // w-stage LDS dest (per buf)
    const int swrow = w * 16 + (l >> 2);
    const _Float16* wsrc0 = wf + (size_t)swrow * 256 + (((l & 3) ^ ((l >> 3) & 3)) * 8);
    int aoff[4];
    #pragma unroll
    for (int m = 0; m < 4; ++m) {
        int row = wc * 64 + m * 16 + (l & 15);
        int g = (l >> 4) ^ ((row >> 1) & 3);
        aoff[m] = row * 32 + g * 8;
    }
    int bbase[4], bx32[4];
    #pragma unroll
    for (int n = 0; n < 4; ++n) {
        int row = wp * 64 + n * 16 + (l & 15);
        int r3 = row & 7;
        bbase[n] = row * 256 + (((l >> 4) ^ (r3 & 3)) * 8);
        bx32[n] = (r3 >> 2) * 32;
    }

    // prologue staging: z (persistent) + w step0 -> buf0
    #pragma unroll
    for (int i = 0; i < 16; ++i) {
        int row = w * 32 + i * 2 + (l >> 5);
        int gc = (l & 31) ^ (row & 7);
        gload16(zf + (size_t)(P0 + row) * NC + gc * 8,
                &zt[w * 8192 + i * 512 + l * 8]);
    }
    gload16(wsrc0, &wt[sdest]);                       // step 0 -> buf 0

    float rbv2[4], rsv2[4];
    int   rbi2[4];
    #pragma unroll
    for (int n = 0; n < 4; ++n) { rbv2[n] = 3.4e38f; rsv2[n] = 3.4e38f; rbi2[n] = 0; }

    __syncthreads();                                  // drains: zt + wt[0] ready

    for (int ct = 0; ct < 8; ++ct) {
        const _Float16* wct = wsrc0 + ct * 32768;
        f32x4 acc[4][4];
        #pragma unroll
        for (int m = 0; m < 4; ++m)
            #pragma unroll
            for (int n = 0; n < 4; ++n)
                #pragma unroll
                for (int e = 0; e < 4; ++e) acc[m][n][e] = 0.0f;

        #pragma unroll
        for (int ks = 0; ks < 8; ++ks) {
            int step = ct * 8 + ks;
            if (step < 63) {                          // stage step+1 -> buf (ks+1)&3
                const _Float16* src = (ks < 7) ? (wct + (ks + 1) * 32)
                                               : (wct + 32768);
                gload16(src, &wt[((ks + 1) & 3) * 4096 + sdest]);
                asm volatile("s_waitcnt vmcnt(1)" ::: "memory");   // own stage(step) landed
            } else {
                asm volatile("s_waitcnt vmcnt(0)" ::: "memory");
            }
            __builtin_amdgcn_sched_barrier(0);
            __builtin_amdgcn_s_barrier();             // raw: no vmcnt drain
            __builtin_amdgcn_sched_barrier(0);
            __builtin_amdgcn_s_setprio(1);
            half8 a[4], b[4];
            #pragma unroll
            for (int m = 0; m < 4; ++m)
                a[m] = *(const half8*)&wt[(ks & 3) * 4096 + aoff[m]];
            #pragma unroll
            for (int n = 0; n < 4; ++n)
                b[n] = *(const half8*)&zt[bbase[n] + ((ks * 32) ^ bx32[n])];
            #pragma unroll
            for (int m = 0; m < 4; ++m)
                #pragma unroll
                for (int n = 0; n < 4; ++n)
                    acc[m][n] = __builtin_amdgcn_mfma_f32_16x16x32_f16(a[m], b[n], acc[m][n], 0, 0, 0);
            __builtin_amdgcn_s_setprio(0);
        }

        // fold into running in-lane top-2 (registers only)
        #pragma unroll
        for (int m = 0; m < 4; ++m) {
            float4 env = *(const float4*)&wsum[ct * 128 + wc * 64 + m * 16 + (l >> 4) * 4];
            const float* en = &env.x;
            #pragma unroll
            for (int n = 0; n < 4; ++n)
                #pragma unroll
                for (int r = 0; r < 4; ++r) {
                    float s = en[r] - acc[m][n][r] * 0.001953125f;  // 2^-9
                    int code = ct * 128 + wc * 64 + m * 16 + (l >> 4) * 4 + r;
                    if (s < rbv2[n]) { rsv2[n] = rbv2[n]; rbv2[n] = s; rbi2[n] = code; }
                    else if (s < rsv2[n]) rsv2[n] = s;  // codes ascend in-lane
                }
        }
    }

    __syncthreads();                                  // all zt/wt reads done before reuse

    // final cross-lane reduce per n; write to bvx (aliases dead wt)
    #pragma unroll
    for (int n = 0; n < 4; ++n) {
        float bv = rbv2[n], sv = rsv2[n];
        int bi = rbi2[n];
        #pragma unroll
        for (int x = 16; x <= 32; x <<= 1) {
            float v2 = __shfl_xor(bv, x);
            float s2 = __shfl_xor(sv, x);
            int   i2 = __shfl_xor(bi, x);
            if (v2 < bv || (v2 == bv && i2 < bi)) { sv = fminf(bv, s2); bv = v2; bi = i2; }
            else sv = fminf(sv, v2);
        }
        if ((l >> 4) == 0) {
            int lp = wp * 64 + n * 16 + l;
            bvx[wc * 256 + lp] = bv;
            svx[wc * 256 + lp] = sv;
            bix[wc * 256 + lp] = bi;
        }
    }
    h[t] = 0;
    h[t + 512] = 0;
    __syncthreads();
    if (t < 256) {                                    // merge the two code-halves
        float bv = bvx[t], sv = svx[t];
        int bi = bix[t];
        float v2 = bvx[256 + t], s2 = svx[256 + t];
        int i2 = bix[256 + t];
        if (v2 < bv || (v2 == bv && i2 < bi)) { sv = fminf(bv, s2); bv = v2; bi = i2; }
        else sv = fminf(sv, v2);
        int pix = P0 + t;
        idxf[pix] = (float)bi;
        idxi[pix] = bi;
        atomicAdd(&h[bi], 1);
        if (sv - bv < GAP_FLAG) {
            int pos = atomicAdd(cnt, 1);
            list[pos] = (ushort_t)pix;
        }
    }
    __syncthreads();
    {
        int v = h[t];
        if (v) { atomicAdd(&ncs[t], (float)v); atomicAdd(&ccount[t], v); }
        v = h[t + 512];
        if (v) { atomicAdd(&ncs[t + 512], (float)v); atomicAdd(&ccount[t + 512], v); }
    }
}

// ================== FALLBACK PATH (round-7 argmin), used if ws too small ====
__global__ __launch_bounds__(256) void argmin_kernel(const float* __restrict__ z,
                                                     const float* __restrict__ w,
                                                     const float* __restrict__ enorm,
                                                     float* __restrict__ idxf,
                                                     int* __restrict__ idxi,
                                                     unsigned long long* __restrict__ flags) {
    __shared__ __align__(16) float smem[64 * 68 + 128 * 68];
    float* zt = smem;
    float* wt = smem + 64 * 68;
    const int t = threadIdx.x;
    const int pr = t & 7;
    const int cr = t >> 3;
    const int P0 = blockIdx.x * 64;
    const int b = P0 >> 12;
    const int hw0 = P0 & (NHW - 1);
    const float* zb = z + (size_t)b * (NC * NHW) + hw0;
    float bestv[8], secv[8];
    int besti[8];
    #pragma unroll
    for (int i = 0; i < 8; ++i) { bestv[i] = 3.4e38f; secv[i] = 3.4e38f; besti[i] = 0; }
    for (int cc = 0; cc < 8; ++cc) {
        float acc[8][4];
        #pragma unroll
        for (int i = 0; i < 8; ++i)
            #pragma unroll
            for (int j = 0; j < 4; ++j) acc[i][j] = 0.0f;
        for (int kc = 0; kc < 4; ++kc) {
            {
                int p = t & 63;
                int k0 = (t >> 6) * 16;
                int f2 = ((p >> 3) & 3) << 2;
                #pragma unroll
                for (int i = 0; i < 16; ++i) {
                    int k = k0 + i;
                    zt[p * 68 + (k ^ f2)] = zb[(size_t)(kc * 64 + k) * NHW + p];
                }
            }
            {
                #pragma unroll
                for (int i = 0; i < 8; ++i) {
                    int f = t + 256 * i;
                    int jj = f >> 4;
                    int k4 = f & 15;
                    float4 v = *(const float4*)&w[(size_t)(cc * 128 + jj) * NC + kc * 64 + k4 * 4];
                    *(float4*)&wt[jj * 68 + k4 * 4] = v;
                }
            }
            __syncthreads();
            #pragma unroll 2
            for (int k = 0; k < 64; k += 4) {
                float4 za[8], wb[4];
                #pragma unroll
                for (int i = 0; i < 8; ++i)
                    za[i] = *(float4*)&zt[(pr + 8 * i) * 68 + (k ^ ((i & 3) << 2))];
                #pragma unroll
                for (int j = 0; j < 4; ++j)
                    wb[j] = *(float4*)&wt[(cr + 32 * j) * 68 + k];
                #pragma unroll
                for (int i = 0; i < 8; ++i)
                    #pragma unroll
                    for (int j = 0; j < 4; ++j)
                        acc[i][j] += za[i].x * wb[j].x + za[i].y * wb[j].y +
                                     za[i].z * wb[j].z + za[i].w * wb[j].w;
            }
            __syncthreads();
        }
        #pragma unroll
        for (int j = 0; j < 4; ++j) {
            int code = cc * 128 + cr + 32 * j;
            float enj = enorm[code];
            #pragma unroll
            for (int i = 0; i < 8; ++i) {
                float s = enj - 2.0f * acc[i][j];
                if (s < bestv[i]) { secv[i] = bestv[i]; bestv[i] = s; besti[i] = code; }
                else if (s < secv[i]) secv[i] = s;
            }
        }
    }
    float* rv = smem;
    int* ri = (int*)(smem + 2048);
    float* rs = smem + 4096;
    #pragma unroll
    for (int i = 0; i < 8; ++i) {
        int p = pr + 8 * i;
        rv[p * 32 + cr] = bestv[i];
        ri[p * 32 + cr] = besti[i];
        rs[p * 32 + cr] = secv[i];
    }
    __syncthreads();
    if (t < 64) {
        int p = t;
        float bv = rv[p * 32], sv = rs[p * 32];
        int bi = ri[p * 32];
        for (int s2 = 1; s2 < 32; ++s2) {
            float v = rv[p * 32 + s2];
            float v2 = rs[p * 32 + s2];
            int ii = ri[p * 32 + s2];
            if (v < bv) { sv = bv; bv = v; bi = ii; }
            else {
                if (v < sv) sv = v;
                if (v == bv && ii < bi) bi = ii;
            }
            if (v2 < sv) sv = v2;
        }
        idxf[P0 + p] = (float)bi;
        idxi[P0 + p] = bi;
        unsigned long long mask = __ballot((sv - bv) < GAP_FLAG);
        if (t == 0) flags[blockIdx.x] = mask;
    }
}

__global__ __launch_bounds__(256) void gather_kernel(const unsigned long long* __restrict__ flags,
                                                     ushort_t* __restrict__ list,
                                                     int* __restrict__ cnt) {
    int p = blockIdx.x * 256 + threadIdx.x;
    unsigned long long m = flags[p >> 6];
    if ((m >> (p & 63)) & 1ULL) {
        int pos = atomicAdd(cnt, 1);
        list[pos] = (ushort_t)p;
    }
}

__global__ __launch_bounds__(1024) void hist_kernel(const int* __restrict__ idxi,
                                                    float* __restrict__ ncs) {
    __shared__ int h[NE];
    int t = threadIdx.x;
    h[t] = 0;
    __syncthreads();
    int gid = blockIdx.x * 1024 + t;
    #pragma unroll
    for (int i = 0; i < 4; ++i) atomicAdd(&h[idxi[gid + i * 16384]], 1);
    __syncthreads();
    if (h[t]) atomicAdd(&ncs[t], (float)h[t]);
}

__global__ __launch_bounds__(1024, 8) void dwloss_kernel(const float* __restrict__ z,
                                                         const float* __restrict__ w,
                                                         const int* __restrict__ idxi,
                                                         float* __restrict__ dw0,
                                                         float* __restrict__ dw1,
                                                         float* __restrict__ lpart) {
    __shared__ float acc[NE];
    __shared__ float wcol[NE];
    __shared__ float ls[16];
    const int c = blockIdx.x;
    const int part = blockIdx.y;
    const int t = threadIdx.x;
    acc[t] = 0.0f;
    wcol[t] = w[(size_t)t * NC + c];
    __syncthreads();
    const float* zc = z + (size_t)c * NHW;
    float lsum = 0.0f;
    #pragma unroll
    for (int half = 0; half < 2; ++half) {
        float4 zv[4];
        int4   iv[4];
        #pragma unroll
        for (int i = 0; i < 4; ++i) {
            int b = part * 8 + half * 4 + i;
            zv[i] = *(const float4*)&zc[(size_t)b * (NC * NHW) + t * 4];
            iv[i] = *(const int4*)&idxi[b * 4096 + t * 4];
        }
        #pragma unroll
        for (int i = 0; i < 4; ++i) {
            float q0 = wcol[iv[i].x], q1 = wcol[iv[i].y];
            float q2 = wcol[iv[i].z], q3 = wcol[iv[i].w];
            float d0 = q0 - zv[i].x, d1 = q1 - zv[i].y;
            float d2 = q2 - zv[i].z, d3 = q3 - zv[i].w;
            lsum += d0 * d0 + d1 * d1 + d2 * d2 + d3 * d3;
            atomicAdd(&acc[iv[i].x], zv[i].x);
            atomicAdd(&acc[iv[i].y], zv[i].y);
            atomicAdd(&acc[iv[i].z], zv[i].z);
            atomicAdd(&acc[iv[i].w], zv[i].w);
        }
    }
    #pragma unroll
    for (int off = 32; off > 0; off >>= 1) lsum += __shfl_down(lsum, off);
    if ((t & 63) == 0) ls[t >> 6] = lsum;
    __syncthreads();
    if (t == 0) {
        float s = 0.0f;
        #pragma unroll
        for (int q = 0; q < 16; ++q) s += ls[q];
        lpart[c * 2 + part] = s;
    }
    float* dwp = part ? dw1 : dw0;
    dwp[(size_t)t * NC + c] = acc[t];
}
// ================== end fallback ============================================

// ---- K1b: np-fp32-mimic re-argmin, 8 flagged pixels per block --------------
__global__ __launch_bounds__(256) void fixup3_kernel(const float* __restrict__ z,
                                                     const float* __restrict__ w,
                                                     const float* __restrict__ wsum,
                                                     const ushort_t* __restrict__ list,
                                                     const int* __restrict__ cnt,
                                                     float* __restrict__ idxf,
                                                     int* __restrict__ idxi,
                                                     float* __restrict__ ncs,
                                                     int* __restrict__ ccount) {
    const int count = cnt[0];
    if (count == 0) return;
    const int ngroups = (count + 7) >> 3;
    const int t = threadIdx.x;

    __shared__ __align__(16) char smem_raw[16384 + 8192];
    double (*zd)[NC] = (double(*)[NC])smem_raw;
    float  (*zf)[NC] = (float(*)[NC])(smem_raw + 16384);
    float* rbv = (float*)(smem_raw + 16384);
    int*   rbi = (int*)smem_raw;
    __shared__ float zs_sh[8];
    __shared__ int   pix_sh[8];
    __shared__ float r2v[8][32];
    __shared__ int   r2i[8][32];

    for (int g = blockIdx.x; g < ngroups; g += gridDim.x) {
        if (t < 8) {
            int i = g * 8 + t;
            pix_sh[t] = (i < count) ? (int)list[i] : (int)list[0];
        }
        __syncthreads();
        #pragma unroll
        for (int px = 0; px < 8; ++px) {
            int p = pix_sh[px];
            int b = p >> 12, hw = p & (NHW - 1);
            float zv = z[(size_t)b * (NC * NHW) + (size_t)t * NHW + hw];
            zf[px][t] = zv;
            zd[px][t] = (double)zv;
        }
        __syncthreads();
        if (t < 8) zs_sh[t] = np_pair128_sq(zf[t]) + np_pair128_sq(zf[t] + 128);
        __syncthreads();

        float zs_reg[8];
        #pragma unroll
        for (int px = 0; px < 8; ++px) zs_reg[px] = zs_sh[px];

        float bvr[8];
        int   bir[8];
        #pragma unroll
        for (int px = 0; px < 8; ++px) { bvr[px] = 3.4e38f; bir[px] = 0; }

        #pragma unroll
        for (int jo = 0; jo < 2; ++jo) {
            const int j0 = t + jo * 512;
            const int j1 = j0 + 256;
            const float* wr0 = w + (size_t)j0 * NC;
            const float* wr1 = w + (size_t)j1 * NC;
            double acc0[8], acc1[8];
            #pragma unroll
            for (int px = 0; px < 8; ++px) { acc0[px] = 0.0; acc1[px] = 0.0; }
            for (int k = 0; k < NC; k += 4) {
                float4 wa = *(const float4*)&wr0[k];
                float4 wb = *(const float4*)&wr1[k];
                const float* wap = (const float*)&wa;
                const float* wbp = (const float*)&wb;
                #pragma unroll
                for (int e = 0; e < 4; ++e) {
                    double wea = (double)wap[e];
                    double web = (double)wbp[e];
                    #pragma unroll
                    for (int px = 0; px < 8; ++px) {
                        double zv = zd[px][k + e];
                        acc0[px] += wea * zv;
                        acc1[px] += web * zv;
                    }
                }
            }
            float ws0 = wsum[j0], ws1 = wsum[j1];
            #pragma unroll
            for (int px = 0; px < 8; ++px) {
                float m0 = (float)acc0[px];
                float s10 = zs_reg[px] + ws0;
                float d0 = s10 - 2.0f * m0;
                if (d0 < bvr[px] || (d0 == bvr[px] && j0 < bir[px])) { bvr[px] = d0; bir[px] = j0; }
                float m1 = (float)acc1[px];
                float s11 = zs_reg[px] + ws1;
                float d1 = s11 - 2.0f * m1;
                if (d1 < bvr[px] || (d1 == bvr[px] && j1 < bir[px])) { bvr[px] = d1; bir[px] = j1; }
            }
        }
        __syncthreads();
        #pragma unroll
        for (int px = 0; px < 8; ++px) {
            rbv[px * 256 + t] = bvr[px];
            rbi[px * 256 + t] = bir[px];
        }
        __syncthreads();
        {
            int px = t >> 5, s = t & 31;
            float bv = rbv[px * 256 + s * 8];
            int   bi = rbi[px * 256 + s * 8];
            #pragma unroll
            for (int e = 1; e < 8; ++e) {
                float v2 = rbv[px * 256 + s * 8 + e];
                int   i2 = rbi[px * 256 + s * 8 + e];
                if (v2 < bv || (v2 == bv && i2 < bi)) { bv = v2; bi = i2; }
            }
            r2v[px][s] = bv;
            r2i[px][s] = bi;
        }
        __syncthreads();
        if (t < 8) {
            float bv = r2v[t][0];
            int   bi = r2i[t][0];
            for (int s = 1; s < 32; ++s) {
                float v2 = r2v[t][s];
                int   i2 = r2i[t][s];
                if (v2 < bv || (v2 == bv && i2 < bi)) { bv = v2; bi = i2; }
            }
            if (g * 8 + t < count) {
                int p = pix_sh[t];
                int old = idxi[p];
                if (old != bi) {
                    idxf[p] = (float)bi;
                    idxi[p] = bi;
                    atomicAdd(&ncs[old], -1.0f);
                    atomicAdd(&ncs[bi], 1.0f);
                    if (ccount) {
                        atomicAdd(&ccount[old], -1);
                        atomicAdd(&ccount[bi], 1);
                    }
                }
            }
        }
        __syncthreads();
    }
}

// ---- K2b: out write only (no z): gather wcol[id] -> out --------------------
__global__ __launch_bounds__(1024, 8) void out2_kernel(const float* __restrict__ w,
                                                       const int* __restrict__ idxi,
                                                       float* __restrict__ outq) {
    __shared__ float wcol[NE];
    const int c = blockIdx.x;
    const int part = blockIdx.y;
    const int t = threadIdx.x;
    wcol[t] = w[(size_t)t * NC + c];
    __syncthreads();
    float* oc = outq + (size_t)c * NHW;
    #pragma unroll
    for (int half = 0; half < 2; ++half) {
        int4 iv[4];
        #pragma unroll
        for (int i = 0; i < 4; ++i) {
            int b = part * 8 + half * 4 + i;
            iv[i] = *(const int4*)&idxi[b * 4096 + t * 4];
        }
        asm volatile("" :: "v"(iv[0].x), "v"(iv[1].x), "v"(iv[2].x), "v"(iv[3].x));
        #pragma unroll
        for (int i = 0; i < 4; ++i) {
            int b = part * 8 + half * 4 + i;
            float4 ov;
            ov.x = wcol[iv[i].x]; ov.y = wcol[iv[i].y];
            ov.z = wcol[iv[i].z]; ov.w = wcol[iv[i].w];
            *(float4*)&oc[(size_t)b * (NC * NHW) + t * 4] = ov;
        }
    }
}

// ---- K2c-1: exclusive prefix scan of per-code counts -----------------------
__global__ __launch_bounds__(1024) void scan_kernel(const int* __restrict__ ccount,
                                                    int* __restrict__ offs,
                                                    int* __restrict__ cur) {
    __shared__ int s[1024];
    int t = threadIdx.x;
    int c0 = ccount[t];
    s[t] = c0;
    __syncthreads();
    for (int off = 1; off < 1024; off <<= 1) {
        int v = (t >= off) ? s[t - off] : 0;
        __syncthreads();
        s[t] += v;
        __syncthreads();
    }
    int ex = s[t] - c0;
    offs[t] = ex;
    cur[t] = ex;
}

// ---- K2c-2: counting-sort scatter: pixels grouped by code ------------------
__global__ __launch_bounds__(256) void scatter2_kernel(const int* __restrict__ idxi,
                                                       int* __restrict__ cur,
                                                       int* __restrict__ sorted) {
    int p = blockIdx.x * 256 + threadIdx.x;
    int id = idxi[p];
    int pos = atomicAdd(&cur[id], 1);
    sorted[pos] = p;
}

// ---- K2c-3: dense segmented dw sum + loss; one wave per (code, half) -------
__global__ __launch_bounds__(256) void dwsum2_kernel(const _Float16* __restrict__ zf,
                                                     const float* __restrict__ w,
                                                     const int* __restrict__ sorted,
                                                     const int* __restrict__ offs,
                                                     const int* __restrict__ ccount,
                                                     float* __restrict__ dw0,
                                                     float* __restrict__ dw1,
                                                     float* __restrict__ lpart) {
    const int t = threadIdx.x, l = t & 63, wv = t >> 6;
    const int j = blockIdx.x * 4 + wv;               // code
    const int part = blockIdx.y;                     // half of this code's list
    const float4 q = *(const float4*)&w[(size_t)j * NC + l * 4];
    const int start = offs[j], cntj = ccount[j];
    const int h0 = (cntj + 1) >> 1;
    const int s = part ? start + h0 : start;
    const int e = part ? start + cntj : start + h0;
    float a0 = 0.f, a1 = 0.f, a2 = 0.f, a3 = 0.f, lsum = 0.f;
    for (int base = s; base < e; base += 64) {
        int pm = (base + l < e) ? sorted[base + l] : 0;
        int nn = min(64, e - base);
        for (int i = 0; i < nn; ++i) {
            int p = __shfl(pm, i);                   // broadcast pixel id
            half4 zv = *(const half4*)&zf[(size_t)p * NC + l * 4];
            float z0 = (float)zv[0], z1 = (float)zv[1];
            float z2 = (float)zv[2], z3 = (float)zv[3];
            a0 += z0; a1 += z1; a2 += z2; a3 += z3;
            float d0 = q.x - z0, d1 = q.y - z1, d2 = q.z - z2, d3 = q.w - z3;
            lsum += d0 * d0 + d1 * d1 + d2 * d2 + d3 * d3;
        }
    }
    float* dwp = part ? dw1 : dw0;
    float4 av = make_float4(a0, a1, a2, a3);
    *(float4*)&dwp[(size_t)j * NC + l * 4] = av;
    #pragma unroll
    for (int off = 32; off > 0; off >>= 1) lsum += __shfl_down(lsum, off);
    if (l == 0) lpart[j * 2 + part] = lsum;
}

// ---- K3: finalize (2048 loss partials) -------------------------------------
__global__ __launch_bounds__(1024) void finalize_kernel(const float* __restrict__ cs,
                                                        const float* __restrict__ lpart,
                                                        float* __restrict__ ncs,
                                                        float* __restrict__ cssm,
                                                        float* __restrict__ loss) {
    int t = threadIdx.x;
    float cnt = ncs[t];
    float v = cs[t] * DECAY + (1.0f - DECAY) * cnt;
    ncs[t] = v;
    __shared__ float red[1024];
    red[t] = v;
    __syncthreads();
    for (int s = 512; s > 0; s >>= 1) {
        if (t < s) red[t] += red[t + s];
        __syncthreads();
    }
    float n = red[0];
    __syncthreads();
    cssm[t] = (v + EPS_) / (n + (float)NE * EPS_) * n;
    red[t] = lpart[t] + lpart[t + 1024];
    __syncthreads();
    for (int s = 512; s > 0; s >>= 1) {
        if (t < s) red[t] += red[t + s];
        __syncthreads();
    }
    if (t == 0) loss[0] = BETA * red[0] / 16777216.0f;
}

// ---- K4: nea + new_weight in-place (nea/nw currently hold dw partials) -----
__global__ __launch_bounds__(256) void neaw_kernel(const float* __restrict__ ea,
                                                   const float* __restrict__ cssm,
                                                   float* __restrict__ nea,
                                                   float* __restrict__ nw) {
    int lin = blockIdx.x * 256 + threadIdx.x;
    float dw = nea[lin] + nw[lin];
    float v = DECAY * ea[lin] + (1.0f - DECAY) * dw;
    nea[lin] = v;
    nw[lin] = v / cssm[lin >> 8];
}

extern "C" void kernel_launch(void* const* d_in, const int* in_sizes, int n_in,
                              void* d_out, int out_size, void* d_ws, size_t ws_size,
                              hipStream_t stream) {
    const float* z  = (const float*)d_in[0];
    const float* w  = (const float*)d_in[1];
    const float* cs = (const float*)d_in[2];
    const float* ea = (const float*)d_in[3];

    float* out  = (float*)d_out;
    float* loss = out + OFF_LOSS;
    float* idxf = out + OFF_IDXF;
    float* ncs  = out + OFF_NCS;
    float* nea  = out + OFF_NEA;
    float* nw   = out + OFF_NW;

    float* wsf = (float*)d_ws;
    float* wsum = wsf + WS_WSUM;
    float* cssm = wsf + WS_CSSM;
    float* lpart = wsf + WS_LPART;
    int* cnt = (int*)(wsf + WS_CNT);
    unsigned long long* flags = (unsigned long long*)(wsf + WS_FLAGS);
    ushort_t* list = (ushort_t*)(wsf + WS_LIST);
    int* idxi = (int*)(wsf + WS_IDXI);
    int* ccount = (int*)(wsf + WS_CCNT);
    int* offs = (int*)(wsf + WS_OFFS);
    int* cur = (int*)(wsf + WS_CUR);
    int* sorted = (int*)(wsf + WS_SORT);

    const bool fast = ws_size >= (size_t)WS_END * 4;

    hipLaunchKernelGGL(wsum_kernel, dim3(16), dim3(64), 0, stream, w, wsum, ncs, cnt,
                       fast ? ccount : cnt, lpart);

    if (fast) {
        _Float16* wf16 = (_Float16*)(wsf + WS_WF16);
        _Float16* zf16 = (_Float16*)(wsf + WS_ZF16);
        hipLaunchKernelGGL(wpack_kernel, dim3(1024), dim3(256), 0, stream, w, wf16);
        hipLaunchKernelGGL(zpack_kernel, dim3(1024, 4), dim3(256), 0, stream, z, zf16);
        hipLaunchKernelGGL(gemm2_kernel, dim3(256), dim3(512), 0, stream,
                           wf16, zf16, wsum, idxf, idxi, list, cnt, ncs, ccount);
        hipLaunchKernelGGL(fixup3_kernel, dim3(256), dim3(256), 0, stream,
                           z, w, wsum, list, cnt, idxf, idxi, ncs, ccount);
        hipLaunchKernelGGL(out2_kernel, dim3(256, 2), dim3(1024), 0, stream, w, idxi, out);
        hipLaunchKernelGGL(scan_kernel, dim3(1), dim3(1024), 0, stream, ccount, offs, cur);
        hipLaunchKernelGGL(scatter2_kernel, dim3(256), dim3(256), 0, stream, idxi, cur, sorted);
        hipLaunchKernelGGL(dwsum2_kernel, dim3(256, 2), dim3(256), 0, stream,
                           zf16, w, sorted, offs, ccount, nea, nw, lpart);
    } else {
        hipLaunchKernelGGL(argmin_kernel, dim3(1024), dim3(256), 0, stream, z, w, wsum, idxf, idxi, flags);
        hipLaunchKernelGGL(gather_kernel, dim3(256), dim3(256), 0, stream, flags, list, cnt);
        hipLaunchKernelGGL(hist_kernel, dim3(16), dim3(1024), 0, stream, idxi, ncs);
        hipLaunchKernelGGL(fixup3_kernel, dim3(256), dim3(256), 0, stream,
                           z, w, wsum, list, cnt, idxf, idxi, ncs, (int*)nullptr);
        hipLaunchKernelGGL(out2_kernel, dim3(256, 2), dim3(1024), 0, stream, w, idxi, out);
        hipLaunchKernelGGL(dwloss_kernel, dim3(256, 2), dim3(1024), 0, stream, z, w, idxi, nea, nw, lpart);
    }

    hipLaunchKernelGGL(finalize_kernel, dim3(1), dim3(1024), 0, stream, cs, lpart, ncs, cssm, loss);
    hipLaunchKernelGGL(neaw_kernel, dim3(1024), dim3(256), 0, stream, ea, cssm, nea, nw);
}

// Round 21
// 246.399 us; speedup vs baseline: 1.1494x; 1.0559x over previous
//
#include <hip/hip_runtime.h>
#include <hip/hip_bf16.h>

typedef unsigned short ushort_t;
typedef __attribute__((ext_vector_type(8))) _Float16 half8;
typedef __attribute__((ext_vector_type(4))) _Float16 half4;
typedef __attribute__((ext_vector_type(4))) float f32x4;

// Problem constants
#define NB    16
#define NC    256
#define NHW   4096
#define NPIX  65536
#define NE    1024
#define BETA  0.25f
#define DECAY 0.99f
#define EPS_  1e-5f
#define GAP_FLAG 1.25e-4f

// d_out layout (floats)
#define OFF_LOSS 16777216
#define OFF_IDXF 16777217
#define OFF_NCS  16842753
#define OFF_NEA  16843777
#define OFF_NW   17105921

// ws layout (float offsets)
#define WS_WSUM  0
#define WS_CSSM  1024
#define WS_LPART 2048                     // 2048 floats (per-code,2 parts)
#define WS_CNT   4096
#define WS_FLAGS 4128
#define WS_LIST  6176                     // 65536 u16 = 32768 floats
#define WS_WF16  40960                    // 1024*256 fp16
#define WS_ZF16  (WS_WF16 + 131072)       // 65536*256 fp16
#define WS_IDXI  (WS_ZF16 + 8388608)      // 65536 int
#define WS_CCNT  (WS_IDXI + 65536)        // 1024 int
#define WS_OFFS  (WS_CCNT + 1024)         // 1024 int
#define WS_CUR   (WS_OFFS + 1024)         // 1024 int
#define WS_SORT  (WS_CUR + 1024)          // 65536 int
#define WS_END   (WS_SORT + 65536)

__device__ __forceinline__ float sq_nofma(float x) {
    float s = x * x;
    asm volatile("" : "+v"(s));
    return s;
}

__device__ __forceinline__ float np_pair128_sq(const float* __restrict__ a) {
    float r[8];
    #pragma unroll
    for (int m = 0; m < 8; ++m) r[m] = sq_nofma(a[m]);
    for (int i = 8; i < 128; i += 8) {
        #pragma unroll
        for (int m = 0; m < 8; ++m) r[m] += sq_nofma(a[i + m]);
    }
    return ((r[0] + r[1]) + (r[2] + r[3])) + ((r[4] + r[5]) + (r[6] + r[7]));
}

__device__ __forceinline__ void gload16(const void* g, void* ldsp) {
    __builtin_amdgcn_global_load_lds((const __attribute__((address_space(1))) unsigned int*)g,
                                     (__attribute__((address_space(3))) unsigned int*)ldsp,
                                     16, 0, 0);
}

// ---- K0b: wsum (np-exact, streaming) + fused fp16 w-pack + inits -----------
// Streaming form of np_pair128_sq: r[m]=0; r[m]+=sq(a[i+m]) i ascending --
// identical accumulation order and combine tree (0+x==x), so bit-exact.
__global__ __launch_bounds__(64) void wsum_kernel(const float* __restrict__ w,
                                                  float* __restrict__ wsum,
                                                  _Float16* __restrict__ wf,   // null in fallback
                                                  float* __restrict__ ncs,
                                                  int* __restrict__ cnt,
                                                  int* __restrict__ ccount,
                                                  float* __restrict__ lpart) {
    int j = blockIdx.x * 64 + threadIdx.x;          // grid 16
    const float* wr = w + (size_t)j * NC;
    float tot[2];
    #pragma unroll
    for (int h = 0; h < 2; ++h) {
        float r[8];
        #pragma unroll
        for (int m = 0; m < 8; ++m) r[m] = 0.0f;
        for (int i = 0; i < 128; i += 8) {
            float4 v0 = *(const float4*)&wr[h * 128 + i];
            float4 v1 = *(const float4*)&wr[h * 128 + i + 4];
            const float* a0 = &v0.x;
            const float* a1 = &v1.x;
            #pragma unroll
            for (int m = 0; m < 4; ++m) {
                r[m]     += sq_nofma(a0[m]);
                r[m + 4] += sq_nofma(a1[m]);
            }
            if (wf) {
                half8 hv;
                #pragma unroll
                for (int m = 0; m < 4; ++m) {
                    hv[m]     = (_Float16)(a0[m] * 1024.0f);
                    hv[m + 4] = (_Float16)(a1[m] * 1024.0f);
                }
                *(half8*)&wf[(size_t)j * NC + h * 128 + i] = hv;
            }
        }
        tot[h] = ((r[0] + r[1]) + (r[2] + r[3])) + ((r[4] + r[5]) + (r[6] + r[7]));
    }
    wsum[j] = tot[0] + tot[1];
    ncs[j] = 0.0f;
    ccount[j] = 0;
    lpart[j] = 0.0f;
    lpart[j + 1024] = 0.0f;
    if (j == 0) cnt[0] = 0;
}

// ---- P2: pack z -> fp16 [65536 pix][256 k] (LDS transpose) -----------------
__global__ __launch_bounds__(256) void zpack_kernel(const float* __restrict__ z,
                                                    _Float16* __restrict__ zf) {
    __shared__ float zs[64 * 65];
    const int t = threadIdx.x;
    const int P0 = blockIdx.x * 64;
    const int b = P0 >> 12, hw0 = P0 & (NHW - 1);
    const int K0 = blockIdx.y * 64;
    const int hw = t & 63, cq = t >> 6;
    const float* zb = z + (size_t)b * (NC * NHW) + hw0 + hw;
    #pragma unroll
    for (int i = 0; i < 16; ++i) {
        int kl = cq * 16 + i;
        zs[hw * 65 + kl] = zb[(size_t)(K0 + kl) * NHW];
    }
    __syncthreads();
    const int p = t >> 2, kq = t & 3;
    size_t obase = (size_t)(P0 + p) * NC + K0 + kq * 16;
    #pragma unroll
    for (int h2 = 0; h2 < 2; ++h2) {
        half8 v;
        #pragma unroll
        for (int j2 = 0; j2 < 8; ++j2)
            v[j2] = (_Float16)zs[p * 65 + kq * 16 + h2 * 8 + j2];
        *(half8*)&zf[obase + h2 * 8] = v;
    }
}

// ---- K1: fp16 MFMA GEMM, quad-buffered wt, counted-vmcnt raw barriers ------
__global__ __launch_bounds__(512) void gemm2_kernel(const _Float16* __restrict__ wf,
                                                    const _Float16* __restrict__ zf,
                                                    const float* __restrict__ wsum,
                                                    float* __restrict__ idxf,
                                                    int* __restrict__ idxi,
                                                    ushort_t* __restrict__ list,
                                                    int* __restrict__ cnt,
                                                    float* __restrict__ ncs,
                                                    int* __restrict__ ccount) {
    __shared__ __align__(16) char smem[163840];       // 128K zt | 4x8K wt
    _Float16* zt = (_Float16*)smem;
    _Float16* wt = (_Float16*)(smem + 131072);
    float* bvx = (float*)(smem + 131072);             // alias wt (post-barrier)
    float* svx = bvx + 512;
    int*   bix = (int*)(svx + 512);
    int*   h   = (int*)smem;                          // alias zt (post-barrier)

    const int t = threadIdx.x;
    const int l = t & 63;
    const int w = t >> 6;                             // 0..7
    const int P0 = blockIdx.x * 256;
    const int wc = w >> 2;                            // code half 0..1
    const int wp = w & 3;                             // px quarter 0..3

    const int sdest = w * 512 + l * 8;                // w-stage LDS dest (per buf)
    const int swrow = w * 16 + (l >> 2);
    const _Float16* wsrc0 = wf + (size_t)swrow * 256 + (((l & 3) ^ ((l >> 3) & 3)) * 8);
    int aoff[4];
    #pragma unroll
    for (int m = 0; m < 4; ++m) {
        int row = wc * 64 + m * 16 + (l & 15);
        int g = (l >> 4) ^ ((row >> 1) & 3);
        aoff[m] = row * 32 + g * 8;
    }
    int bbase[4], bx32[4];
    #pragma unroll
    for (int n = 0; n < 4; ++n) {
        int row = wp * 64 + n * 16 + (l & 15);
        int r3 = row & 7;
        bbase[n] = row * 256 + (((l >> 4) ^ (r3 & 3)) * 8);
        bx32[n] = (r3 >> 2) * 32;
    }

    #pragma unroll
    for (int i = 0; i < 16; ++i) {
        int row = w * 32 + i * 2 + (l >> 5);
        int gc = (l & 31) ^ (row & 7);
        gload16(zf + (size_t)(P0 + row) * NC + gc * 8,
                &zt[w * 8192 + i * 512 + l * 8]);
    }
    gload16(wsrc0, &wt[sdest]);                       // step 0 -> buf 0

    float rbv2[4], rsv2[4];
    int   rbi2[4];
    #pragma unroll
    for (int n = 0; n < 4; ++n) { rbv2[n] = 3.4e38f; rsv2[n] = 3.4e38f; rbi2[n] = 0; }

    __syncthreads();                                  // drains: zt + wt[0] ready

    for (int ct = 0; ct < 8; ++ct) {
        const _Float16* wct = wsrc0 + ct * 32768;
        f32x4 acc[4][4];
        #pragma unroll
        for (int m = 0; m < 4; ++m)
            #pragma unroll
            for (int n = 0; n < 4; ++n)
                #pragma unroll
                for (int e = 0; e < 4; ++e) acc[m][n][e] = 0.0f;

        #pragma unroll
        for (int ks = 0; ks < 8; ++ks) {
            int step = ct * 8 + ks;
            if (step < 63) {                          // stage step+1 -> buf (ks+1)&3
                const _Float16* src = (ks < 7) ? (wct + (ks + 1) * 32)
                                               : (wct + 32768);
                gload16(src, &wt[((ks + 1) & 3) * 4096 + sdest]);
                asm volatile("s_waitcnt vmcnt(1)" ::: "memory");   // own stage(step) landed
            } else {
                asm volatile("s_waitcnt vmcnt(0)" ::: "memory");
            }
            __builtin_amdgcn_sched_barrier(0);
            __builtin_amdgcn_s_barrier();             // raw: no vmcnt drain
            __builtin_amdgcn_sched_barrier(0);
            __builtin_amdgcn_s_setprio(1);
            half8 a[4], b[4];
            #pragma unroll
            for (int m = 0; m < 4; ++m)
                a[m] = *(const half8*)&wt[(ks & 3) * 4096 + aoff[m]];
            #pragma unroll
            for (int n = 0; n < 4; ++n)
                b[n] = *(const half8*)&zt[bbase[n] + ((ks * 32) ^ bx32[n])];
            #pragma unroll
            for (int m = 0; m < 4; ++m)
                #pragma unroll
                for (int n = 0; n < 4; ++n)
                    acc[m][n] = __builtin_amdgcn_mfma_f32_16x16x32_f16(a[m], b[n], acc[m][n], 0, 0, 0);
            __builtin_amdgcn_s_setprio(0);
        }

        // fold into running in-lane top-2 (registers only)
        #pragma unroll
        for (int m = 0; m < 4; ++m) {
            float4 env = *(const float4*)&wsum[ct * 128 + wc * 64 + m * 16 + (l >> 4) * 4];
            const float* en = &env.x;
            #pragma unroll
            for (int n = 0; n < 4; ++n)
                #pragma unroll
                for (int r = 0; r < 4; ++r) {
                    float s = en[r] - acc[m][n][r] * 0.001953125f;  // 2^-9
                    int code = ct * 128 + wc * 64 + m * 16 + (l >> 4) * 4 + r;
                    if (s < rbv2[n]) { rsv2[n] = rbv2[n]; rbv2[n] = s; rbi2[n] = code; }
                    else if (s < rsv2[n]) rsv2[n] = s;  // codes ascend in-lane
                }
        }
    }

    __syncthreads();                                  // all zt/wt reads done before reuse

    #pragma unroll
    for (int n = 0; n < 4; ++n) {
        float bv = rbv2[n], sv = rsv2[n];
        int bi = rbi2[n];
        #pragma unroll
        for (int x = 16; x <= 32; x <<= 1) {
            float v2 = __shfl_xor(bv, x);
            float s2 = __shfl_xor(sv, x);
            int   i2 = __shfl_xor(bi, x);
            if (v2 < bv || (v2 == bv && i2 < bi)) { sv = fminf(bv, s2); bv = v2; bi = i2; }
            else sv = fminf(sv, v2);
        }
        if ((l >> 4) == 0) {
            int lp = wp * 64 + n * 16 + l;
            bvx[wc * 256 + lp] = bv;
            svx[wc * 256 + lp] = sv;
            bix[wc * 256 + lp] = bi;
        }
    }
    h[t] = 0;
    h[t + 512] = 0;
    __syncthreads();
    if (t < 256) {                                    // merge the two code-halves
        float bv = bvx[t], sv = svx[t];
        int bi = bix[t];
        float v2 = bvx[256 + t], s2 = svx[256 + t];
        int i2 = bix[256 + t];
        if (v2 < bv || (v2 == bv && i2 < bi)) { sv = fminf(bv, s2); bv = v2; bi = i2; }
        else sv = fminf(sv, v2);
        int pix = P0 + t;
        idxf[pix] = (float)bi;
        idxi[pix] = bi;
        atomicAdd(&h[bi], 1);
        if (sv - bv < GAP_FLAG) {
            int pos = atomicAdd(cnt, 1);
            list[pos] = (ushort_t)pix;
        }
    }
    __syncthreads();
    {
        int v = h[t];
        if (v) { atomicAdd(&ncs[t], (float)v); atomicAdd(&ccount[t], v); }
        v = h[t + 512];
        if (v) { atomicAdd(&ncs[t + 512], (float)v); atomicAdd(&ccount[t + 512], v); }
    }
}

// ================== FALLBACK PATH (round-7 argmin), used if ws too small ====
__global__ __launch_bounds__(256) void argmin_kernel(const float* __restrict__ z,
                                                     const float* __restrict__ w,
                                                     const float* __restrict__ enorm,
                                                     float* __restrict__ idxf,
                                                     int* __restrict__ idxi,
                                                     unsigned long long* __restrict__ flags) {
    __shared__ __align__(16) float smem[64 * 68 + 128 * 68];
    float* zt = smem;
    float* wt = smem + 64 * 68;
    const int t = threadIdx.x;
    const int pr = t & 7;
    const int cr = t >> 3;
    const int P0 = blockIdx.x * 64;
    const int b = P0 >> 12;
    const int hw0 = P0 & (NHW - 1);
    const float* zb = z + (size_t)b * (NC * NHW) + hw0;
    float bestv[8], secv[8];
    int besti[8];
    #pragma unroll
    for (int i = 0; i < 8; ++i) { bestv[i] = 3.4e38f; secv[i] = 3.4e38f; besti[i] = 0; }
    for (int cc = 0; cc < 8; ++cc) {
        float acc[8][4];
        #pragma unroll
        for (int i = 0; i < 8; ++i)
            #pragma unroll
            for (int j = 0; j < 4; ++j) acc[i][j] = 0.0f;
        for (int kc = 0; kc < 4; ++kc) {
            {
                int p = t & 63;
                int k0 = (t >> 6) * 16;
                int f2 = ((p >> 3) & 3) << 2;
                #pragma unroll
                for (int i = 0; i < 16; ++i) {
                    int k = k0 + i;
                    zt[p * 68 + (k ^ f2)] = zb[(size_t)(kc * 64 + k) * NHW + p];
                }
            }
            {
                #pragma unroll
                for (int i = 0; i < 8; ++i) {
                    int f = t + 256 * i;
                    int jj = f >> 4;
                    int k4 = f & 15;
                    float4 v = *(const float4*)&w[(size_t)(cc * 128 + jj) * NC + kc * 64 + k4 * 4];
                    *(float4*)&wt[jj * 68 + k4 * 4] = v;
                }
            }
            __syncthreads();
            #pragma unroll 2
            for (int k = 0; k < 64; k += 4) {
                float4 za[8], wb[4];
                #pragma unroll
                for (int i = 0; i < 8; ++i)
                    za[i] = *(float4*)&zt[(pr + 8 * i) * 68 + (k ^ ((i & 3) << 2))];
                #pragma unroll
                for (int j = 0; j < 4; ++j)
                    wb[j] = *(float4*)&wt[(cr + 32 * j) * 68 + k];
                #pragma unroll
                for (int i = 0; i < 8; ++i)
                    #pragma unroll
                    for (int j = 0; j < 4; ++j)
                        acc[i][j] += za[i].x * wb[j].x + za[i].y * wb[j].y +
                                     za[i].z * wb[j].z + za[i].w * wb[j].w;
            }
            __syncthreads();
        }
        #pragma unroll
        for (int j = 0; j < 4; ++j) {
            int code = cc * 128 + cr + 32 * j;
            float enj = enorm[code];
            #pragma unroll
            for (int i = 0; i < 8; ++i) {
                float s = enj - 2.0f * acc[i][j];
                if (s < bestv[i]) { secv[i] = bestv[i]; bestv[i] = s; besti[i] = code; }
                else if (s < secv[i]) secv[i] = s;
            }
        }
    }
    float* rv = smem;
    int* ri = (int*)(smem + 2048);
    float* rs = smem + 4096;
    #pragma unroll
    for (int i = 0; i < 8; ++i) {
        int p = pr + 8 * i;
        rv[p * 32 + cr] = bestv[i];
        ri[p * 32 + cr] = besti[i];
        rs[p * 32 + cr] = secv[i];
    }
    __syncthreads();
    if (t < 64) {
        int p = t;
        float bv = rv[p * 32], sv = rs[p * 32];
        int bi = ri[p * 32];
        for (int s2 = 1; s2 < 32; ++s2) {
            float v = rv[p * 32 + s2];
            float v2 = rs[p * 32 + s2];
            int ii = ri[p * 32 + s2];
            if (v < bv) { sv = bv; bv = v; bi = ii; }
            else {
                if (v < sv) sv = v;
                if (v == bv && ii < bi) bi = ii;
            }
            if (v2 < sv) sv = v2;
        }
        idxf[P0 + p] = (float)bi;
        idxi[P0 + p] = bi;
        unsigned long long mask = __ballot((sv - bv) < GAP_FLAG);
        if (t == 0) flags[blockIdx.x] = mask;
    }
}

__global__ __launch_bounds__(256) void gather_kernel(const unsigned long long* __restrict__ flags,
                                                     ushort_t* __restrict__ list,
                                                     int* __restrict__ cnt) {
    int p = blockIdx.x * 256 + threadIdx.x;
    unsigned long long m = flags[p >> 6];
    if ((m >> (p & 63)) & 1ULL) {
        int pos = atomicAdd(cnt, 1);
        list[pos] = (ushort_t)p;
    }
}

__global__ __launch_bounds__(1024) void hist_kernel(const int* __restrict__ idxi,
                                                    float* __restrict__ ncs) {
    __shared__ int h[NE];
    int t = threadIdx.x;
    h[t] = 0;
    __syncthreads();
    int gid = blockIdx.x * 1024 + t;
    #pragma unroll
    for (int i = 0; i < 4; ++i) atomicAdd(&h[idxi[gid + i * 16384]], 1);
    __syncthreads();
    if (h[t]) atomicAdd(&ncs[t], (float)h[t]);
}

__global__ __launch_bounds__(1024, 8) void dwloss_kernel(const float* __restrict__ z,
                                                         const float* __restrict__ w,
                                                         const int* __restrict__ idxi,
                                                         float* __restrict__ dw0,
                                                         float* __restrict__ dw1,
                                                         float* __restrict__ lpart) {
    __shared__ float acc[NE];
    __shared__ float wcol[NE];
    __shared__ float ls[16];
    const int c = blockIdx.x;
    const int part = blockIdx.y;
    const int t = threadIdx.x;
    acc[t] = 0.0f;
    wcol[t] = w[(size_t)t * NC + c];
    __syncthreads();
    const float* zc = z + (size_t)c * NHW;
    float lsum = 0.0f;
    #pragma unroll
    for (int half = 0; half < 2; ++half) {
        float4 zv[4];
        int4   iv[4];
        #pragma unroll
        for (int i = 0; i < 4; ++i) {
            int b = part * 8 + half * 4 + i;
            zv[i] = *(const float4*)&zc[(size_t)b * (NC * NHW) + t * 4];
            iv[i] = *(const int4*)&idxi[b * 4096 + t * 4];
        }
        #pragma unroll
        for (int i = 0; i < 4; ++i) {
            float q0 = wcol[iv[i].x], q1 = wcol[iv[i].y];
            float q2 = wcol[iv[i].z], q3 = wcol[iv[i].w];
            float d0 = q0 - zv[i].x, d1 = q1 - zv[i].y;
            float d2 = q2 - zv[i].z, d3 = q3 - zv[i].w;
            lsum += d0 * d0 + d1 * d1 + d2 * d2 + d3 * d3;
            atomicAdd(&acc[iv[i].x], zv[i].x);
            atomicAdd(&acc[iv[i].y], zv[i].y);
            atomicAdd(&acc[iv[i].z], zv[i].z);
            atomicAdd(&acc[iv[i].w], zv[i].w);
        }
    }
    #pragma unroll
    for (int off = 32; off > 0; off >>= 1) lsum += __shfl_down(lsum, off);
    if ((t & 63) == 0) ls[t >> 6] = lsum;
    __syncthreads();
    if (t == 0) {
        float s = 0.0f;
        #pragma unroll
        for (int q = 0; q < 16; ++q) s += ls[q];
        lpart[c * 2 + part] = s;
    }
    float* dwp = part ? dw1 : dw0;
    dwp[(size_t)t * NC + c] = acc[t];
}
// ================== end fallback ============================================

// ---- K1b: np-fp32-mimic re-argmin, 8 flagged pixels per block --------------
__global__ __launch_bounds__(256) void fixup3_kernel(const float* __restrict__ z,
                                                     const float* __restrict__ w,
                                                     const float* __restrict__ wsum,
                                                     const ushort_t* __restrict__ list,
                                                     const int* __restrict__ cnt,
                                                     float* __restrict__ idxf,
                                                     int* __restrict__ idxi,
                                                     float* __restrict__ ncs,
                                                     int* __restrict__ ccount) {
    const int count = cnt[0];
    if (count == 0) return;
    const int ngroups = (count + 7) >> 3;
    const int t = threadIdx.x;

    __shared__ __align__(16) char smem_raw[16384 + 8192];
    double (*zd)[NC] = (double(*)[NC])smem_raw;
    float  (*zf)[NC] = (float(*)[NC])(smem_raw + 16384);
    float* rbv = (float*)(smem_raw + 16384);
    int*   rbi = (int*)smem_raw;
    __shared__ float zs_sh[8];
    __shared__ int   pix_sh[8];
    __shared__ float r2v[8][32];
    __shared__ int   r2i[8][32];

    for (int g = blockIdx.x; g < ngroups; g += gridDim.x) {
        if (t < 8) {
            int i = g * 8 + t;
            pix_sh[t] = (i < count) ? (int)list[i] : (int)list[0];
        }
        __syncthreads();
        #pragma unroll
        for (int px = 0; px < 8; ++px) {
            int p = pix_sh[px];
            int b = p >> 12, hw = p & (NHW - 1);
            float zv = z[(size_t)b * (NC * NHW) + (size_t)t * NHW + hw];
            zf[px][t] = zv;
            zd[px][t] = (double)zv;
        }
        __syncthreads();
        if (t < 8) zs_sh[t] = np_pair128_sq(zf[t]) + np_pair128_sq(zf[t] + 128);
        __syncthreads();

        float zs_reg[8];
        #pragma unroll
        for (int px = 0; px < 8; ++px) zs_reg[px] = zs_sh[px];

        float bvr[8];
        int   bir[8];
        #pragma unroll
        for (int px = 0; px < 8; ++px) { bvr[px] = 3.4e38f; bir[px] = 0; }

        #pragma unroll
        for (int jo = 0; jo < 2; ++jo) {
            const int j0 = t + jo * 512;
            const int j1 = j0 + 256;
            const float* wr0 = w + (size_t)j0 * NC;
            const float* wr1 = w + (size_t)j1 * NC;
            double acc0[8], acc1[8];
            #pragma unroll
            for (int px = 0; px < 8; ++px) { acc0[px] = 0.0; acc1[px] = 0.0; }
            for (int k = 0; k < NC; k += 4) {
                float4 wa = *(const float4*)&wr0[k];
                float4 wb = *(const float4*)&wr1[k];
                const float* wap = (const float*)&wa;
                const float* wbp = (const float*)&wb;
                #pragma unroll
                for (int e = 0; e < 4; ++e) {
                    double wea = (double)wap[e];
                    double web = (double)wbp[e];
                    #pragma unroll
                    for (int px = 0; px < 8; ++px) {
                        double zv = zd[px][k + e];
                        acc0[px] += wea * zv;
                        acc1[px] += web * zv;
                    }
                }
            }
            float ws0 = wsum[j0], ws1 = wsum[j1];
            #pragma unroll
            for (int px = 0; px < 8; ++px) {
                float m0 = (float)acc0[px];
                float s10 = zs_reg[px] + ws0;
                float d0 = s10 - 2.0f * m0;
                if (d0 < bvr[px] || (d0 == bvr[px] && j0 < bir[px])) { bvr[px] = d0; bir[px] = j0; }
                float m1 = (float)acc1[px];
                float s11 = zs_reg[px] + ws1;
                float d1 = s11 - 2.0f * m1;
                if (d1 < bvr[px] || (d1 == bvr[px] && j1 < bir[px])) { bvr[px] = d1; bir[px] = j1; }
            }
        }
        __syncthreads();
        #pragma unroll
        for (int px = 0; px < 8; ++px) {
            rbv[px * 256 + t] = bvr[px];
            rbi[px * 256 + t] = bir[px];
        }
        __syncthreads();
        {
            int px = t >> 5, s = t & 31;
            float bv = rbv[px * 256 + s * 8];
            int   bi = rbi[px * 256 + s * 8];
            #pragma unroll
            for (int e = 1; e < 8; ++e) {
                float v2 = rbv[px * 256 + s * 8 + e];
                int   i2 = rbi[px * 256 + s * 8 + e];
                if (v2 < bv || (v2 == bv && i2 < bi)) { bv = v2; bi = i2; }
            }
            r2v[px][s] = bv;
            r2i[px][s] = bi;
        }
        __syncthreads();
        if (t < 8) {
            float bv = r2v[t][0];
            int   bi = r2i[t][0];
            for (int s = 1; s < 32; ++s) {
                float v2 = r2v[t][s];
                int   i2 = r2i[t][s];
                if (v2 < bv || (v2 == bv && i2 < bi)) { bv = v2; bi = i2; }
            }
            if (g * 8 + t < count) {
                int p = pix_sh[t];
                int old = idxi[p];
                if (old != bi) {
                    idxf[p] = (float)bi;
                    idxi[p] = bi;
                    atomicAdd(&ncs[old], -1.0f);
                    atomicAdd(&ncs[bi], 1.0f);
                    if (ccount) {
                        atomicAdd(&ccount[old], -1);
                        atomicAdd(&ccount[bi], 1);
                    }
                }
            }
        }
        __syncthreads();
    }
}

// ---- K2b: out write only (no z): gather wcol[id] -> out; 4-way batch split -
__global__ __launch_bounds__(1024, 8) void out2_kernel(const float* __restrict__ w,
                                                       const int* __restrict__ idxi,
                                                       float* __restrict__ outq) {
    __shared__ float wcol[NE];
    const int c = blockIdx.x;
    const int part = blockIdx.y;                      // 0..3
    const int t = threadIdx.x;
    wcol[t] = w[(size_t)t * NC + c];
    __syncthreads();
    float* oc = outq + (size_t)c * NHW;
    int4 iv[4];
    #pragma unroll
    for (int i = 0; i < 4; ++i) {
        int b = part * 4 + i;
        iv[i] = *(const int4*)&idxi[b * 4096 + t * 4];
    }
    asm volatile("" :: "v"(iv[0].x), "v"(iv[1].x), "v"(iv[2].x), "v"(iv[3].x));
    #pragma unroll
    for (int i = 0; i < 4; ++i) {
        int b = part * 4 + i;
        float4 ov;
        ov.x = wcol[iv[i].x]; ov.y = wcol[iv[i].y];
        ov.z = wcol[iv[i].z]; ov.w = wcol[iv[i].w];
        *(float4*)&oc[(size_t)b * (NC * NHW) + t * 4] = ov;
    }
}

// ---- K2c-1: exclusive prefix scan of per-code counts -----------------------
__global__ __launch_bounds__(1024) void scan_kernel(const int* __restrict__ ccount,
                                                    int* __restrict__ offs,
                                                    int* __restrict__ cur) {
    __shared__ int s[1024];
    int t = threadIdx.x;
    int c0 = ccount[t];
    s[t] = c0;
    __syncthreads();
    for (int off = 1; off < 1024; off <<= 1) {
        int v = (t >= off) ? s[t - off] : 0;
        __syncthreads();
        s[t] += v;
        __syncthreads();
    }
    int ex = s[t] - c0;
    offs[t] = ex;
    cur[t] = ex;
}

// ---- K2c-2: counting-sort scatter: pixels grouped by code ------------------
__global__ __launch_bounds__(256) void scatter2_kernel(const int* __restrict__ idxi,
                                                       int* __restrict__ cur,
                                                       int* __restrict__ sorted) {
    int p = blockIdx.x * 256 + threadIdx.x;
    int id = idxi[p];
    int pos = atomicAdd(&cur[id], 1);
    sorted[pos] = p;
}

// ---- K2c-3: dense segmented dw sum + loss; one wave per (code, half) -------
__global__ __launch_bounds__(256) void dwsum2_kernel(const _Float16* __restrict__ zf,
                                                     const float* __restrict__ w,
                                                     const int* __restrict__ sorted,
                                                     const int* __restrict__ offs,
                                                     const int* __restrict__ ccount,
                                                     float* __restrict__ dw0,
                                                     float* __restrict__ dw1,
                                                     float* __restrict__ lpart) {
    const int t = threadIdx.x, l = t & 63, wv = t >> 6;
    const int j = blockIdx.x * 4 + wv;               // code
    const int part = blockIdx.y;                     // half of this code's list
    const float4 q = *(const float4*)&w[(size_t)j * NC + l * 4];
    const int start = offs[j], cntj = ccount[j];
    const int h0 = (cntj + 1) >> 1;
    const int s = part ? start + h0 : start;
    const int e = part ? start + cntj : start + h0;
    float a0 = 0.f, a1 = 0.f, a2 = 0.f, a3 = 0.f, lsum = 0.f;
    for (int base = s; base < e; base += 64) {
        int pm = (base + l < e) ? sorted[base + l] : 0;
        int nn = min(64, e - base);
        for (int i = 0; i < nn; ++i) {
            int p = __shfl(pm, i);                   // broadcast pixel id
            half4 zv = *(const half4*)&zf[(size_t)p * NC + l * 4];
            float z0 = (float)zv[0], z1 = (float)zv[1];
            float z2 = (float)zv[2], z3 = (float)zv[3];
            a0 += z0; a1 += z1; a2 += z2; a3 += z3;
            float d0 = q.x - z0, d1 = q.y - z1, d2 = q.z - z2, d3 = q.w - z3;
            lsum += d0 * d0 + d1 * d1 + d2 * d2 + d3 * d3;
        }
    }
    float* dwp = part ? dw1 : dw0;
    float4 av = make_float4(a0, a1, a2, a3);
    *(float4*)&dwp[(size_t)j * NC + l * 4] = av;
    #pragma unroll
    for (int off = 32; off > 0; off >>= 1) lsum += __shfl_down(lsum, off);
    if (l == 0) lpart[j * 2 + part] = lsum;
}

// ---- K3: finalize (2048 loss partials) -------------------------------------
__global__ __launch_bounds__(1024) void finalize_kernel(const float* __restrict__ cs,
                                                        const float* __restrict__ lpart,
                                                        float* __restrict__ ncs,
                                                        float* __restrict__ cssm,
                                                        float* __restrict__ loss) {
    int t = threadIdx.x;
    float cnt = ncs[t];
    float v = cs[t] * DECAY + (1.0f - DECAY) * cnt;
    ncs[t] = v;
    __shared__ float red[1024];
    red[t] = v;
    __syncthreads();
    for (int s = 512; s > 0; s >>= 1) {
        if (t < s) red[t] += red[t + s];
        __syncthreads();
    }
    float n = red[0];
    __syncthreads();
    cssm[t] = (v + EPS_) / (n + (float)NE * EPS_) * n;
    red[t] = lpart[t] + lpart[t + 1024];
    __syncthreads();
    for (int s = 512; s > 0; s >>= 1) {
        if (t < s) red[t] += red[t + s];
        __syncthreads();
    }
    if (t == 0) loss[0] = BETA * red[0] / 16777216.0f;
}

// ---- K4: nea + new_weight in-place (nea/nw currently hold dw partials) -----
__global__ __launch_bounds__(256) void neaw_kernel(const float* __restrict__ ea,
                                                   const float* __restrict__ cssm,
                                                   float* __restrict__ nea,
                                                   float* __restrict__ nw) {
    int lin = blockIdx.x * 256 + threadIdx.x;
    float dw = nea[lin] + nw[lin];
    float v = DECAY * ea[lin] + (1.0f - DECAY) * dw;
    nea[lin] = v;
    nw[lin] = v / cssm[lin >> 8];
}

extern "C" void kernel_launch(void* const* d_in, const int* in_sizes, int n_in,
                              void* d_out, int out_size, void* d_ws, size_t ws_size,
                              hipStream_t stream) {
    const float* z  = (const float*)d_in[0];
    const float* w  = (const float*)d_in[1];
    const float* cs = (const float*)d_in[2];
    const float* ea = (const float*)d_in[3];

    float* out  = (float*)d_out;
    float* loss = out + OFF_LOSS;
    float* idxf = out + OFF_IDXF;
    float* ncs  = out + OFF_NCS;
    float* nea  = out + OFF_NEA;
    float* nw   = out + OFF_NW;

    float* wsf = (float*)d_ws;
    float* wsum = wsf + WS_WSUM;
    float* cssm = wsf + WS_CSSM;
    float* lpart = wsf + WS_LPART;
    int* cnt = (int*)(wsf + WS_CNT);
    unsigned long long* flags = (unsigned long long*)(wsf + WS_FLAGS);
    ushort_t* list = (ushort_t*)(wsf + WS_LIST);
    int* idxi = (int*)(wsf + WS_IDXI);
    int* ccount = (int*)(wsf + WS_CCNT);
    int* offs = (int*)(wsf + WS_OFFS);
    int* cur = (int*)(wsf + WS_CUR);
    int* sorted = (int*)(wsf + WS_SORT);

    const bool fast = ws_size >= (size_t)WS_END * 4;
    _Float16* wf16 = (_Float16*)(wsf + WS_WF16);
    _Float16* zf16 = (_Float16*)(wsf + WS_ZF16);

    hipLaunchKernelGGL(wsum_kernel, dim3(16), dim3(64), 0, stream, w, wsum,
                       fast ? wf16 : (_Float16*)nullptr, ncs, cnt, ccount, lpart);

    if (fast) {
        hipLaunchKernelGGL(zpack_kernel, dim3(1024, 4), dim3(256), 0, stream, z, zf16);
        hipLaunchKernelGGL(gemm2_kernel, dim3(256), dim3(512), 0, stream,
                           wf16, zf16, wsum, idxf, idxi, list, cnt, ncs, ccount);
        hipLaunchKernelGGL(fixup3_kernel, dim3(256), dim3(256), 0, stream,
                           z, w, wsum, list, cnt, idxf, idxi, ncs, ccount);
        hipLaunchKernelGGL(out2_kernel, dim3(256, 4), dim3(1024), 0, stream, w, idxi, out);
        hipLaunchKernelGGL(scan_kernel, dim3(1), dim3(1024), 0, stream, ccount, offs, cur);
        hipLaunchKernelGGL(scatter2_kernel, dim3(256), dim3(256), 0, stream, idxi, cur, sorted);
        hipLaunchKernelGGL(dwsum2_kernel, dim3(256, 2), dim3(256), 0, stream,
                           zf16, w, sorted, offs, ccount, nea, nw, lpart);
    } else {
        hipLaunchKernelGGL(argmin_kernel, dim3(1024), dim3(256), 0, stream, z, w, wsum, idxf, idxi, flags);
        hipLaunchKernelGGL(gather_kernel, dim3(256), dim3(256), 0, stream, flags, list, cnt);
        hipLaunchKernelGGL(hist_kernel, dim3(16), dim3(1024), 0, stream, idxi, ncs);
        hipLaunchKernelGGL(fixup3_kernel, dim3(256), dim3(256), 0, stream,
                           z, w, wsum, list, cnt, idxf, idxi, ncs, (int*)nullptr);
        hipLaunchKernelGGL(out2_kernel, dim3(256, 4), dim3(1024), 0, stream, w, idxi, out);
        hipLaunchKernelGGL(dwloss_kernel, dim3(256, 2), dim3(1024), 0, stream, z, w, idxi, nea, nw, lpart);
    }

    hipLaunchKernelGGL(finalize_kernel, dim3(1), dim3(1024), 0, stream, cs, lpart, ncs, cssm, loss);
    hipLaunchKernelGGL(neaw_kernel, dim3(1024), dim3(256), 0, stream, ea, cssm, nea, nw);
}